// Round 1
// baseline (1560.528 us; speedup 1.0000x reference)
//
#include <hip/hip_runtime.h>

#define N_NODES 100000
#define N_EDGES 25000
#define K 128
#define NNZ 1600000

// ---------------- softmax over rows of y -> probs ----------------
// one wave (64 lanes) per row; each lane owns 2 of the 128 columns.
__global__ __launch_bounds__(256) void softmax_k(const float* __restrict__ y,
                                                 float* __restrict__ probs) {
    int wid = threadIdx.x >> 6;
    int lane = threadIdx.x & 63;
    int row = blockIdx.x * 4 + wid;
    if (row >= N_NODES) return;
    const float* yr = y + (size_t)row * K;
    float a = yr[lane];
    float b = yr[lane + 64];
    float m = fmaxf(a, b);
    #pragma unroll
    for (int off = 32; off >= 1; off >>= 1) m = fmaxf(m, __shfl_xor(m, off, 64));
    float e0 = expf(a - m);
    float e1 = expf(b - m);
    float s = e0 + e1;
    #pragma unroll
    for (int off = 32; off >= 1; off >>= 1) s += __shfl_xor(s, off, 64);
    float inv = 1.0f / s;
    float* pr = probs + (size_t)row * K;
    pr[lane]      = e0 * inv;
    pr[lane + 64] = e1 * inv;
}

// ---------------- degree counts ----------------
__global__ __launch_bounds__(256) void deg_k(const int* __restrict__ ni,
                                             const int* __restrict__ ei,
                                             float* __restrict__ node_deg,
                                             float* __restrict__ edge_deg) {
    int i = blockIdx.x * 256 + threadIdx.x;
    if (i >= NNZ) return;
    atomicAdd(&node_deg[ni[i]], 1.0f);
    atomicAdd(&edge_deg[ei[i]], 1.0f);
}

// ---------------- scatter probs[node] += into edge_agg[edge] ----------------
// one wave per incidence entry; lane covers cols {lane, lane+64}.
__global__ __launch_bounds__(256) void scat_edge_k(const float* __restrict__ probs,
                                                   const int* __restrict__ ni,
                                                   const int* __restrict__ ei,
                                                   float* __restrict__ edge_agg) {
    int wid = threadIdx.x >> 6, lane = threadIdx.x & 63;
    int e = blockIdx.x * 4 + wid;
    if (e >= NNZ) return;
    int n = ni[e], h = ei[e];
    const float* pr = probs + (size_t)n * K;
    float* ea = edge_agg + (size_t)h * K;
    atomicAdd(&ea[lane],      pr[lane]);
    atomicAdd(&ea[lane + 64], pr[lane + 64]);
}

// ---------------- edge_feat = (edge_agg / max(deg,1)) @ W ----------------
// block = 256 threads handles 16 edge-rows; thread (j = tid&127) computes
// column j for 8 rows. W row k is coalesced across j; A rows broadcast from LDS.
#define MM_ROWS 16
__global__ __launch_bounds__(256) void mm_k(const float* __restrict__ edge_agg,
                                            const float* __restrict__ edge_deg,
                                            const float* __restrict__ W,
                                            float* __restrict__ edge_feat) {
    __shared__ float a_s[MM_ROWS][K];
    int row0 = blockIdx.x * MM_ROWS;
    for (int t = threadIdx.x; t < MM_ROWS * K; t += 256) {
        int r = t >> 7, c = t & 127;
        int row = row0 + r;
        float v = 0.0f;
        if (row < N_EDGES) {
            float scale = 1.0f / fmaxf(edge_deg[row], 1.0f);
            v = edge_agg[(size_t)row * K + c] * scale;
        }
        a_s[r][c] = v;
    }
    __syncthreads();
    int j = threadIdx.x & 127;
    int rg = threadIdx.x >> 7;   // 0..1 -> rows rg*8 .. rg*8+7
    float acc[8];
    #pragma unroll
    for (int r = 0; r < 8; ++r) acc[r] = 0.0f;
    for (int k = 0; k < K; ++k) {
        float w = W[k * K + j];
        #pragma unroll
        for (int r = 0; r < 8; ++r) acc[r] = fmaf(a_s[rg * 8 + r][k], w, acc[r]);
    }
    #pragma unroll
    for (int r = 0; r < 8; ++r) {
        int row = row0 + rg * 8 + r;
        if (row < N_EDGES) edge_feat[(size_t)row * K + j] = acc[r];
    }
}

// ---------------- scatter edge_feat[edge] += into out[node] ----------------
__global__ __launch_bounds__(256) void scat_node_k(const float* __restrict__ edge_feat,
                                                   const int* __restrict__ ni,
                                                   const int* __restrict__ ei,
                                                   float* __restrict__ out) {
    int wid = threadIdx.x >> 6, lane = threadIdx.x & 63;
    int e = blockIdx.x * 4 + wid;
    if (e >= NNZ) return;
    int n = ni[e], h = ei[e];
    const float* ef = edge_feat + (size_t)h * K;
    float* o = out + (size_t)n * K;
    atomicAdd(&o[lane],      ef[lane]);
    atomicAdd(&o[lane + 64], ef[lane + 64]);
}

// ---------------- finalize: nat_grad = clip(p)*acc/deg; out = nat - rowmean ----
__global__ __launch_bounds__(256) void fin_k(const float* __restrict__ probs,
                                             const float* __restrict__ node_deg,
                                             float* __restrict__ out) {
    int wid = threadIdx.x >> 6, lane = threadIdx.x & 63;
    int row = blockIdx.x * 4 + wid;
    if (row >= N_NODES) return;
    float inv = 1.0f / fmaxf(node_deg[row], 1.0f);
    size_t base = (size_t)row * K;
    float p0 = fmaxf(probs[base + lane],      1e-12f);
    float p1 = fmaxf(probs[base + lane + 64], 1e-12f);
    float v0 = p0 * (out[base + lane]      * inv);
    float v1 = p1 * (out[base + lane + 64] * inv);
    float s = v0 + v1;
    #pragma unroll
    for (int off = 32; off >= 1; off >>= 1) s += __shfl_xor(s, off, 64);
    float mean = s * (1.0f / (float)K);
    out[base + lane]      = v0 - mean;
    out[base + lane + 64] = v1 - mean;
}

extern "C" void kernel_launch(void* const* d_in, const int* in_sizes, int n_in,
                              void* d_out, int out_size, void* d_ws, size_t ws_size,
                              hipStream_t stream) {
    const float* y        = (const float*)d_in[0];
    const float* W        = (const float*)d_in[1];
    const int*   node_idx = (const int*)d_in[2];
    const int*   edge_idx = (const int*)d_in[3];
    float* out = (float*)d_out;

    float* probs     = (float*)d_ws;                       // N_NODES*K
    float* edge_agg  = probs + (size_t)N_NODES * K;        // N_EDGES*K
    float* edge_feat = edge_agg + (size_t)N_EDGES * K;     // N_EDGES*K
    float* edge_deg  = edge_feat + (size_t)N_EDGES * K;    // N_EDGES
    float* node_deg  = edge_deg + N_EDGES;                 // N_NODES

    hipMemsetAsync(edge_agg, 0, (size_t)N_EDGES * K * sizeof(float), stream);
    hipMemsetAsync(edge_deg, 0, (size_t)(N_EDGES + N_NODES) * sizeof(float), stream);
    hipMemsetAsync(out,      0, (size_t)N_NODES * K * sizeof(float), stream);

    softmax_k  <<<(N_NODES + 3) / 4,   256, 0, stream>>>(y, probs);
    deg_k      <<<(NNZ + 255) / 256,   256, 0, stream>>>(node_idx, edge_idx, node_deg, edge_deg);
    scat_edge_k<<<(NNZ + 3) / 4,       256, 0, stream>>>(probs, node_idx, edge_idx, edge_agg);
    mm_k       <<<(N_EDGES + MM_ROWS - 1) / MM_ROWS, 256, 0, stream>>>(edge_agg, edge_deg, W, edge_feat);
    scat_node_k<<<(NNZ + 3) / 4,       256, 0, stream>>>(edge_feat, node_idx, edge_idx, out);
    fin_k      <<<(N_NODES + 3) / 4,   256, 0, stream>>>(probs, node_deg, out);
}

// Round 2
// 618.850 us; speedup vs baseline: 2.5217x; 2.5217x over previous
//
#include <hip/hip_runtime.h>

#define N_NODES 100000
#define N_EDGES 25000
#define K 128
#define NNZ 1600000

// ---------------- softmax over rows of y -> probs ----------------
__global__ __launch_bounds__(256) void softmax_k(const float* __restrict__ y,
                                                 float* __restrict__ probs) {
    int wid = threadIdx.x >> 6;
    int lane = threadIdx.x & 63;
    int row = blockIdx.x * 4 + wid;
    if (row >= N_NODES) return;
    const float* yr = y + (size_t)row * K;
    float a = yr[lane];
    float b = yr[lane + 64];
    float m = fmaxf(a, b);
    #pragma unroll
    for (int off = 32; off >= 1; off >>= 1) m = fmaxf(m, __shfl_xor(m, off, 64));
    float e0 = expf(a - m);
    float e1 = expf(b - m);
    float s = e0 + e1;
    #pragma unroll
    for (int off = 32; off >= 1; off >>= 1) s += __shfl_xor(s, off, 64);
    float inv = 1.0f / s;
    float* pr = probs + (size_t)row * K;
    pr[lane]      = e0 * inv;
    pr[lane + 64] = e1 * inv;
}

// ---------------- histogram of node/edge indices ----------------
__global__ __launch_bounds__(256) void hist_k(const int* __restrict__ ni,
                                              const int* __restrict__ ei,
                                              int* __restrict__ n_cnt,
                                              int* __restrict__ e_cnt) {
    int i = blockIdx.x * 256 + threadIdx.x;
    if (i >= NNZ) return;
    atomicAdd(&n_cnt[ni[i]], 1);
    atomicAdd(&e_cnt[ei[i]], 1);
}

// ---------------- 3-phase exclusive scan (counts -> offsets) ----------------
__global__ __launch_bounds__(1024) void scan1_k(const int* __restrict__ cnt,
                                                int* __restrict__ off,
                                                int* __restrict__ part, int n) {
    __shared__ int s[1024];
    int t = threadIdx.x;
    int i = blockIdx.x * 1024 + t;
    int v = (i < n) ? cnt[i] : 0;
    s[t] = v;
    __syncthreads();
    for (int d = 1; d < 1024; d <<= 1) {
        int add = (t >= d) ? s[t - d] : 0;
        __syncthreads();
        s[t] += add;
        __syncthreads();
    }
    if (i < n) off[i] = s[t] - v;          // exclusive within block
    if (t == 1023) part[blockIdx.x] = s[1023];
}

__global__ __launch_bounds__(1024) void scan2_k(int* __restrict__ part, int n) {
    __shared__ int s[1024];
    int t = threadIdx.x;
    int v = (t < n) ? part[t] : 0;
    s[t] = v;
    __syncthreads();
    for (int d = 1; d < 1024; d <<= 1) {
        int add = (t >= d) ? s[t - d] : 0;
        __syncthreads();
        s[t] += add;
        __syncthreads();
    }
    if (t < n) part[t] = s[t] - v;         // exclusive scan of block totals
}

__global__ __launch_bounds__(1024) void scan3_k(int* __restrict__ off,
                                                const int* __restrict__ part,
                                                int n, int total) {
    int i = blockIdx.x * 1024 + threadIdx.x;
    if (i < n) off[i] += part[blockIdx.x];
    if (i == 0) off[n] = total;
}

// ---------------- fill both CSR adjacency arrays ----------------
__global__ __launch_bounds__(256) void fill_k(const int* __restrict__ ni,
                                              const int* __restrict__ ei,
                                              const int* __restrict__ n_off,
                                              const int* __restrict__ e_off,
                                              int* __restrict__ n_cur,
                                              int* __restrict__ e_cur,
                                              int* __restrict__ n_edges,
                                              int* __restrict__ e_nodes) {
    int i = blockIdx.x * 256 + threadIdx.x;
    if (i >= NNZ) return;
    int n = ni[i], h = ei[i];
    int pe = atomicAdd(&e_cur[h], 1);
    e_nodes[e_off[h] + pe] = n;
    int pn = atomicAdd(&n_cur[n], 1);
    n_edges[n_off[n] + pn] = h;
}

// ------- fused: gather probs -> edge mean (LDS) -> @W -> edge_feat -------
// block = 256 (4 waves) handles 16 edges. Wave w gathers edges w*4..w*4+3
// accumulating in registers; then classic LDS-broadcast 16x128 @ 128x128.
__global__ __launch_bounds__(256) void mm2_k(const float* __restrict__ probs,
                                             const int* __restrict__ e_off,
                                             const int* __restrict__ e_nodes,
                                             const float* __restrict__ W,
                                             float* __restrict__ edge_feat) {
    __shared__ float a_s[16][K];
    int row0 = blockIdx.x * 16;
    int wid = threadIdx.x >> 6, lane = threadIdx.x & 63;

    for (int rr = 0; rr < 4; ++rr) {
        int e = row0 + wid * 4 + rr;
        float a0 = 0.0f, a1 = 0.0f;
        if (e < N_EDGES) {
            int beg = e_off[e], end = e_off[e + 1];
            int j = beg;
            for (; j + 3 < end; j += 4) {
                int h0 = e_nodes[j], h1 = e_nodes[j + 1];
                int h2 = e_nodes[j + 2], h3 = e_nodes[j + 3];
                const float* p0 = probs + (size_t)h0 * K;
                const float* p1 = probs + (size_t)h1 * K;
                const float* p2 = probs + (size_t)h2 * K;
                const float* p3 = probs + (size_t)h3 * K;
                a0 += p0[lane] + p1[lane] + p2[lane] + p3[lane];
                a1 += p0[lane + 64] + p1[lane + 64] + p2[lane + 64] + p3[lane + 64];
            }
            for (; j < end; ++j) {
                const float* p = probs + (size_t)e_nodes[j] * K;
                a0 += p[lane];
                a1 += p[lane + 64];
            }
            float inv = 1.0f / fmaxf((float)(end - beg), 1.0f);
            a0 *= inv; a1 *= inv;
        }
        a_s[wid * 4 + rr][lane]      = a0;
        a_s[wid * 4 + rr][lane + 64] = a1;
    }
    __syncthreads();

    int jcol = threadIdx.x & 127;
    int rg = threadIdx.x >> 7;             // 0..1 -> rows rg*8 .. rg*8+7
    float acc[8];
    #pragma unroll
    for (int r = 0; r < 8; ++r) acc[r] = 0.0f;
    for (int k = 0; k < K; ++k) {
        float w = W[k * K + jcol];
        #pragma unroll
        for (int r = 0; r < 8; ++r) acc[r] = fmaf(a_s[rg * 8 + r][k], w, acc[r]);
    }
    #pragma unroll
    for (int r = 0; r < 8; ++r) {
        int row = row0 + rg * 8 + r;
        if (row < N_EDGES) edge_feat[(size_t)row * K + jcol] = acc[r];
    }
}

// ------- fused: gather edge_feat -> node mean; nat-grad; mean-center -------
__global__ __launch_bounds__(256) void node_fin_k(const float* __restrict__ probs,
                                                  const int* __restrict__ n_off,
                                                  const int* __restrict__ n_edges,
                                                  const float* __restrict__ edge_feat,
                                                  float* __restrict__ out) {
    int wid = threadIdx.x >> 6, lane = threadIdx.x & 63;
    int row = blockIdx.x * 4 + wid;
    if (row >= N_NODES) return;
    int beg = n_off[row], end = n_off[row + 1];
    float a0 = 0.0f, a1 = 0.0f;
    int j = beg;
    for (; j + 3 < end; j += 4) {
        int h0 = n_edges[j], h1 = n_edges[j + 1];
        int h2 = n_edges[j + 2], h3 = n_edges[j + 3];
        const float* f0 = edge_feat + (size_t)h0 * K;
        const float* f1 = edge_feat + (size_t)h1 * K;
        const float* f2 = edge_feat + (size_t)h2 * K;
        const float* f3 = edge_feat + (size_t)h3 * K;
        a0 += f0[lane] + f1[lane] + f2[lane] + f3[lane];
        a1 += f0[lane + 64] + f1[lane + 64] + f2[lane + 64] + f3[lane + 64];
    }
    for (; j < end; ++j) {
        const float* f = edge_feat + (size_t)n_edges[j] * K;
        a0 += f[lane];
        a1 += f[lane + 64];
    }
    float inv = 1.0f / fmaxf((float)(end - beg), 1.0f);
    size_t base = (size_t)row * K;
    float p0 = fmaxf(probs[base + lane],      1e-12f);
    float p1 = fmaxf(probs[base + lane + 64], 1e-12f);
    float v0 = p0 * (a0 * inv);
    float v1 = p1 * (a1 * inv);
    float s = v0 + v1;
    #pragma unroll
    for (int off = 32; off >= 1; off >>= 1) s += __shfl_xor(s, off, 64);
    float mean = s * (1.0f / (float)K);
    out[base + lane]      = v0 - mean;
    out[base + lane + 64] = v1 - mean;
}

extern "C" void kernel_launch(void* const* d_in, const int* in_sizes, int n_in,
                              void* d_out, int out_size, void* d_ws, size_t ws_size,
                              hipStream_t stream) {
    const float* y        = (const float*)d_in[0];
    const float* W        = (const float*)d_in[1];
    const int*   node_idx = (const int*)d_in[2];
    const int*   edge_idx = (const int*)d_in[3];
    float* out = (float*)d_out;

    // workspace carve-up (all 4-byte elements)
    int* ip = (int*)d_ws;
    int* e_cnt   = ip;                       // 25000   (also reused as fill cursor)
    int* n_cnt   = e_cnt + N_EDGES;          // 100000  (also reused as fill cursor)
    int* e_off   = n_cnt + N_NODES;          // 25001
    int* n_off   = e_off + (N_EDGES + 1);    // 100001
    int* part_e  = n_off + (N_NODES + 1);    // 128
    int* part_n  = part_e + 128;             // 128
    int* e_nodes = part_n + 128;             // NNZ
    int* n_edges = e_nodes + NNZ;            // NNZ
    float* probs     = (float*)(n_edges + NNZ);          // N_NODES*K
    float* edge_feat = probs + (size_t)N_NODES * K;      // N_EDGES*K

    const int GE = (N_EDGES + 1023) / 1024;   // 25 blocks
    const int GN = (N_NODES + 1023) / 1024;   // 98 blocks

    hipMemsetAsync(e_cnt, 0, (size_t)(N_EDGES + N_NODES) * sizeof(int), stream);

    softmax_k<<<(N_NODES + 3) / 4, 256, 0, stream>>>(y, probs);
    hist_k   <<<(NNZ + 255) / 256, 256, 0, stream>>>(node_idx, edge_idx, n_cnt, e_cnt);

    scan1_k<<<GE, 1024, 0, stream>>>(e_cnt, e_off, part_e, N_EDGES);
    scan2_k<<<1,  1024, 0, stream>>>(part_e, GE);
    scan3_k<<<GE, 1024, 0, stream>>>(e_off, part_e, N_EDGES, NNZ);

    scan1_k<<<GN, 1024, 0, stream>>>(n_cnt, n_off, part_n, N_NODES);
    scan2_k<<<1,  1024, 0, stream>>>(part_n, GN);
    scan3_k<<<GN, 1024, 0, stream>>>(n_off, part_n, N_NODES, NNZ);

    // reuse cnt arrays as fill cursors
    hipMemsetAsync(e_cnt, 0, (size_t)(N_EDGES + N_NODES) * sizeof(int), stream);
    fill_k<<<(NNZ + 255) / 256, 256, 0, stream>>>(node_idx, edge_idx, n_off, e_off,
                                                  n_cnt, e_cnt, n_edges, e_nodes);

    mm2_k<<<(N_EDGES + 15) / 16, 256, 0, stream>>>(probs, e_off, e_nodes, W, edge_feat);
    node_fin_k<<<(N_NODES + 3) / 4, 256, 0, stream>>>(probs, n_off, n_edges, edge_feat, out);
}

// Round 3
// 394.823 us; speedup vs baseline: 3.9525x; 1.5674x over previous
//
#include <hip/hip_runtime.h>

#define N_NODES 100000
#define N_EDGES 25000
#define K 128
#define NNZ 1600000

// edge buckets: 128 edges each; node buckets: 512 nodes each
#define NB_E 196   // ceil(25000/128)
#define NB_N 196   // ceil(100000/512)
// packed entry: (edge << 17) | node   (edge < 2^15, node < 2^17)

// ---------------- softmax over rows of y -> probs (float2) ----------------
__global__ __launch_bounds__(256) void softmax_k(const float* __restrict__ y,
                                                 float* __restrict__ probs) {
    int wid = threadIdx.x >> 6, lane = threadIdx.x & 63;
    int row = blockIdx.x * 4 + wid;
    if (row >= N_NODES) return;
    const float2* yr = (const float2*)(y + (size_t)row * K);
    float2 a = yr[lane];
    float m = fmaxf(a.x, a.y);
    #pragma unroll
    for (int off = 32; off >= 1; off >>= 1) m = fmaxf(m, __shfl_xor(m, off, 64));
    float e0 = expf(a.x - m);
    float e1 = expf(a.y - m);
    float s = e0 + e1;
    #pragma unroll
    for (int off = 32; off >= 1; off >>= 1) s += __shfl_xor(s, off, 64);
    float inv = 1.0f / s;
    float2* pr = (float2*)(probs + (size_t)row * K);
    pr[lane] = make_float2(e0 * inv, e1 * inv);
}

// ---------------- bucket histogram (both sides) ----------------
__global__ __launch_bounds__(256) void bhist_k(const int* __restrict__ ni,
                                               const int* __restrict__ ei,
                                               int* __restrict__ ebcnt,
                                               int* __restrict__ nbcnt) {
    __shared__ int se[NB_E], sn[NB_N];
    for (int t = threadIdx.x; t < NB_E; t += 256) se[t] = 0;
    for (int t = threadIdx.x; t < NB_N; t += 256) sn[t] = 0;
    __syncthreads();
    for (int i = blockIdx.x * 256 + threadIdx.x; i < NNZ; i += gridDim.x * 256) {
        atomicAdd(&se[ei[i] >> 7], 1);
        atomicAdd(&sn[ni[i] >> 9], 1);
    }
    __syncthreads();
    for (int t = threadIdx.x; t < NB_E; t += 256) if (se[t]) atomicAdd(&ebcnt[t], se[t]);
    for (int t = threadIdx.x; t < NB_N; t += 256) if (sn[t]) atomicAdd(&nbcnt[t], sn[t]);
}

// ---------------- scan bucket counts -> offsets + cursors ----------------
__global__ __launch_bounds__(512) void bscan_k(const int* __restrict__ ebcnt,
                                               const int* __restrict__ nbcnt,
                                               int* __restrict__ ebOff, int* __restrict__ nbOff,
                                               int* __restrict__ ebCur, int* __restrict__ nbCur,
                                               int* __restrict__ e_off, int* __restrict__ n_off) {
    __shared__ int s[512];
    int t = threadIdx.x;
    int half = t >> 8, idx = t & 255;
    int v = 0;
    if (half == 0) v = (idx < NB_E) ? ebcnt[idx] : 0;
    else           v = (idx < NB_N) ? nbcnt[idx] : 0;
    s[t] = v;
    __syncthreads();
    for (int d = 1; d < 256; d <<= 1) {
        int add = (idx >= d) ? s[t - d] : 0;
        __syncthreads();
        s[t] += add;
        __syncthreads();
    }
    int excl = s[t] - v;
    if (half == 0 && idx < NB_E) {
        ebOff[idx] = excl; ebCur[idx] = excl;
        if (idx == NB_E - 1) ebOff[NB_E] = excl + v;
    }
    if (half == 1 && idx < NB_N) {
        nbOff[idx] = excl; nbCur[idx] = excl;
        if (idx == NB_N - 1) nbOff[NB_N] = excl + v;
    }
    if (t == 0) { e_off[N_EDGES] = NNZ; n_off[N_NODES] = NNZ; }
}

// ---------------- partition entries into buckets (both sides) ----------------
__global__ __launch_bounds__(256) void bpart_k(const int* __restrict__ ni,
                                               const int* __restrict__ ei,
                                               int* __restrict__ ebCur, int* __restrict__ nbCur,
                                               unsigned* __restrict__ ebkt,
                                               unsigned* __restrict__ nbkt) {
    __shared__ int cnt[NB_E > NB_N ? NB_E : NB_N];
    __shared__ int runb[NB_E > NB_N ? NB_E : NB_N];
    unsigned pk[8]; int rk[8]; bool val[8];
    int i0 = blockIdx.x * 2048;
    #pragma unroll
    for (int k = 0; k < 8; ++k) {
        int i = i0 + threadIdx.x + k * 256;
        val[k] = (i < NNZ);
        pk[k] = val[k] ? (((unsigned)ei[i] << 17) | (unsigned)ni[i]) : 0u;
    }
    // ---- edge side: bucket = pk >> 24 ----
    for (int t = threadIdx.x; t < NB_E; t += 256) cnt[t] = 0;
    __syncthreads();
    #pragma unroll
    for (int k = 0; k < 8; ++k) if (val[k]) rk[k] = atomicAdd(&cnt[pk[k] >> 24], 1);
    __syncthreads();
    for (int t = threadIdx.x; t < NB_E; t += 256)
        runb[t] = cnt[t] ? atomicAdd(&ebCur[t], cnt[t]) : 0;
    __syncthreads();
    #pragma unroll
    for (int k = 0; k < 8; ++k) if (val[k]) ebkt[runb[pk[k] >> 24] + rk[k]] = pk[k];
    __syncthreads();
    // ---- node side: bucket = (pk >> 9) & 0xFF ----
    for (int t = threadIdx.x; t < NB_N; t += 256) cnt[t] = 0;
    __syncthreads();
    #pragma unroll
    for (int k = 0; k < 8; ++k) if (val[k]) rk[k] = atomicAdd(&cnt[(pk[k] >> 9) & 0xFF], 1);
    __syncthreads();
    for (int t = threadIdx.x; t < NB_N; t += 256)
        runb[t] = cnt[t] ? atomicAdd(&nbCur[t], cnt[t]) : 0;
    __syncthreads();
    #pragma unroll
    for (int k = 0; k < 8; ++k) if (val[k]) nbkt[runb[(pk[k] >> 9) & 0xFF] + rk[k]] = pk[k];
}

// ------- per-bucket: counts -> local scan -> csr offsets + ranked fill -------
__global__ __launch_bounds__(256) void bfill_k(const unsigned* __restrict__ ebkt,
                                               const unsigned* __restrict__ nbkt,
                                               const int* __restrict__ ebOff,
                                               const int* __restrict__ nbOff,
                                               int* __restrict__ e_off, int* __restrict__ n_off,
                                               int* __restrict__ e_nodes,
                                               int* __restrict__ n_edges) {
    __shared__ int cnt[512];
    __shared__ int par[256];
    int b = blockIdx.x;
    int t = threadIdx.x;
    if (b < NB_E) {
        int beg = ebOff[b], end = ebOff[b + 1];
        for (int x = t; x < 128; x += 256) cnt[x] = 0;
        __syncthreads();
        int i = beg + t;
        for (; i + 768 < end; i += 1024) {
            unsigned p0 = ebkt[i], p1 = ebkt[i + 256], p2 = ebkt[i + 512], p3 = ebkt[i + 768];
            atomicAdd(&cnt[(p0 >> 17) & 127], 1);
            atomicAdd(&cnt[(p1 >> 17) & 127], 1);
            atomicAdd(&cnt[(p2 >> 17) & 127], 1);
            atomicAdd(&cnt[(p3 >> 17) & 127], 1);
        }
        for (; i < end; i += 256) atomicAdd(&cnt[(ebkt[i] >> 17) & 127], 1);
        __syncthreads();
        int v = (t < 128) ? cnt[t] : 0;
        par[t] = v;
        __syncthreads();
        for (int d = 1; d < 256; d <<= 1) {
            int add = (t >= d) ? par[t - d] : 0;
            __syncthreads();
            par[t] += add;
            __syncthreads();
        }
        if (t < 128) {
            int excl = par[t] - v;
            cnt[t] = excl;
            int e = (b << 7) + t;
            if (e < N_EDGES) e_off[e] = beg + excl;
        }
        __syncthreads();
        i = beg + t;
        for (; i + 768 < end; i += 1024) {
            unsigned p0 = ebkt[i], p1 = ebkt[i + 256], p2 = ebkt[i + 512], p3 = ebkt[i + 768];
            int d0 = atomicAdd(&cnt[(p0 >> 17) & 127], 1);
            int d1 = atomicAdd(&cnt[(p1 >> 17) & 127], 1);
            int d2 = atomicAdd(&cnt[(p2 >> 17) & 127], 1);
            int d3 = atomicAdd(&cnt[(p3 >> 17) & 127], 1);
            e_nodes[beg + d0] = p0 & 0x1FFFF;
            e_nodes[beg + d1] = p1 & 0x1FFFF;
            e_nodes[beg + d2] = p2 & 0x1FFFF;
            e_nodes[beg + d3] = p3 & 0x1FFFF;
        }
        for (; i < end; i += 256) {
            unsigned p = ebkt[i];
            int d = atomicAdd(&cnt[(p >> 17) & 127], 1);
            e_nodes[beg + d] = p & 0x1FFFF;
        }
    } else {
        int b2 = b - NB_E;
        int beg = nbOff[b2], end = nbOff[b2 + 1];
        for (int x = t; x < 512; x += 256) cnt[x] = 0;
        __syncthreads();
        int i = beg + t;
        for (; i + 768 < end; i += 1024) {
            unsigned p0 = nbkt[i], p1 = nbkt[i + 256], p2 = nbkt[i + 512], p3 = nbkt[i + 768];
            atomicAdd(&cnt[p0 & 511], 1);
            atomicAdd(&cnt[p1 & 511], 1);
            atomicAdd(&cnt[p2 & 511], 1);
            atomicAdd(&cnt[p3 & 511], 1);
        }
        for (; i < end; i += 256) atomicAdd(&cnt[nbkt[i] & 511], 1);
        __syncthreads();
        int v0 = cnt[t * 2], v1 = cnt[t * 2 + 1];
        int vs = v0 + v1;
        par[t] = vs;
        __syncthreads();
        for (int d = 1; d < 256; d <<= 1) {
            int add = (t >= d) ? par[t - d] : 0;
            __syncthreads();
            par[t] += add;
            __syncthreads();
        }
        int excl = par[t] - vs;
        __syncthreads();
        cnt[t * 2] = excl;
        cnt[t * 2 + 1] = excl + v0;
        int n = (b2 << 9) + t * 2;
        if (n < N_NODES)     n_off[n]     = beg + excl;
        if (n + 1 < N_NODES) n_off[n + 1] = beg + excl + v0;
        __syncthreads();
        i = beg + t;
        for (; i + 768 < end; i += 1024) {
            unsigned p0 = nbkt[i], p1 = nbkt[i + 256], p2 = nbkt[i + 512], p3 = nbkt[i + 768];
            int d0 = atomicAdd(&cnt[p0 & 511], 1);
            int d1 = atomicAdd(&cnt[p1 & 511], 1);
            int d2 = atomicAdd(&cnt[p2 & 511], 1);
            int d3 = atomicAdd(&cnt[p3 & 511], 1);
            n_edges[beg + d0] = p0 >> 17;
            n_edges[beg + d1] = p1 >> 17;
            n_edges[beg + d2] = p2 >> 17;
            n_edges[beg + d3] = p3 >> 17;
        }
        for (; i < end; i += 256) {
            unsigned p = nbkt[i];
            int d = atomicAdd(&cnt[p & 511], 1);
            n_edges[beg + d] = p >> 17;
        }
    }
}

// ------- fused: gather probs -> edge mean (LDS) -> @W -> edge_feat -------
__global__ __launch_bounds__(256) void mm2_k(const float* __restrict__ probs,
                                             const int* __restrict__ e_off,
                                             const int* __restrict__ e_nodes,
                                             const float* __restrict__ W,
                                             float* __restrict__ edge_feat) {
    __shared__ float a_s[16][K];
    int row0 = blockIdx.x * 16;
    int wid = threadIdx.x >> 6, lane = threadIdx.x & 63;

    for (int rr = 0; rr < 4; ++rr) {
        int e = row0 + wid * 4 + rr;
        float ax = 0.f, ay = 0.f, bx = 0.f, by = 0.f, cx = 0.f, cy = 0.f, dx = 0.f, dy = 0.f;
        if (e < N_EDGES) {
            int beg = e_off[e], end = e_off[e + 1];
            int j = beg;
            for (; j + 3 < end; j += 4) {
                int h0 = e_nodes[j], h1 = e_nodes[j + 1];
                int h2 = e_nodes[j + 2], h3 = e_nodes[j + 3];
                float2 q0 = *(const float2*)(probs + (size_t)h0 * K + 2 * lane);
                float2 q1 = *(const float2*)(probs + (size_t)h1 * K + 2 * lane);
                float2 q2 = *(const float2*)(probs + (size_t)h2 * K + 2 * lane);
                float2 q3 = *(const float2*)(probs + (size_t)h3 * K + 2 * lane);
                ax += q0.x; ay += q0.y; bx += q1.x; by += q1.y;
                cx += q2.x; cy += q2.y; dx += q3.x; dy += q3.y;
            }
            for (; j < end; ++j) {
                float2 q = *(const float2*)(probs + (size_t)e_nodes[j] * K + 2 * lane);
                ax += q.x; ay += q.y;
            }
            float inv = 1.0f / fmaxf((float)(end - beg), 1.0f);
            ax = (ax + bx + cx + dx) * inv;
            ay = (ay + by + cy + dy) * inv;
        }
        *(float2*)(&a_s[wid * 4 + rr][2 * lane]) = make_float2(ax, ay);
    }
    __syncthreads();

    int jcol = threadIdx.x & 127;
    int rg = threadIdx.x >> 7;
    float acc[8];
    #pragma unroll
    for (int r = 0; r < 8; ++r) acc[r] = 0.0f;
    for (int k = 0; k < K; ++k) {
        float w = W[k * K + jcol];
        #pragma unroll
        for (int r = 0; r < 8; ++r) acc[r] = fmaf(a_s[rg * 8 + r][k], w, acc[r]);
    }
    #pragma unroll
    for (int r = 0; r < 8; ++r) {
        int row = row0 + rg * 8 + r;
        if (row < N_EDGES) edge_feat[(size_t)row * K + jcol] = acc[r];
    }
}

// ------- fused: gather edge_feat -> node mean; nat-grad; mean-center -------
__global__ __launch_bounds__(256) void node_fin_k(const float* __restrict__ probs,
                                                  const int* __restrict__ n_off,
                                                  const int* __restrict__ n_edges,
                                                  const float* __restrict__ edge_feat,
                                                  float* __restrict__ out) {
    int wid = threadIdx.x >> 6, lane = threadIdx.x & 63;
    int row = blockIdx.x * 4 + wid;
    if (row >= N_NODES) return;
    int beg = n_off[row], end = n_off[row + 1];
    float ax = 0.f, ay = 0.f, bx = 0.f, by = 0.f, cx = 0.f, cy = 0.f, dx = 0.f, dy = 0.f;
    int j = beg;
    for (; j + 3 < end; j += 4) {
        int h0 = n_edges[j], h1 = n_edges[j + 1];
        int h2 = n_edges[j + 2], h3 = n_edges[j + 3];
        float2 q0 = *(const float2*)(edge_feat + (size_t)h0 * K + 2 * lane);
        float2 q1 = *(const float2*)(edge_feat + (size_t)h1 * K + 2 * lane);
        float2 q2 = *(const float2*)(edge_feat + (size_t)h2 * K + 2 * lane);
        float2 q3 = *(const float2*)(edge_feat + (size_t)h3 * K + 2 * lane);
        ax += q0.x; ay += q0.y; bx += q1.x; by += q1.y;
        cx += q2.x; cy += q2.y; dx += q3.x; dy += q3.y;
    }
    for (; j < end; ++j) {
        float2 q = *(const float2*)(edge_feat + (size_t)n_edges[j] * K + 2 * lane);
        ax += q.x; ay += q.y;
    }
    float inv = 1.0f / fmaxf((float)(end - beg), 1.0f);
    float2 p = *(const float2*)(probs + (size_t)row * K + 2 * lane);
    float v0 = fmaxf(p.x, 1e-12f) * ((ax + bx + cx + dx) * inv);
    float v1 = fmaxf(p.y, 1e-12f) * ((ay + by + cy + dy) * inv);
    float s = v0 + v1;
    #pragma unroll
    for (int off = 32; off >= 1; off >>= 1) s += __shfl_xor(s, off, 64);
    float mean = s * (1.0f / (float)K);
    *(float2*)(out + (size_t)row * K + 2 * lane) = make_float2(v0 - mean, v1 - mean);
}

extern "C" void kernel_launch(void* const* d_in, const int* in_sizes, int n_in,
                              void* d_out, int out_size, void* d_ws, size_t ws_size,
                              hipStream_t stream) {
    const float* y        = (const float*)d_in[0];
    const float* W        = (const float*)d_in[1];
    const int*   node_idx = (const int*)d_in[2];
    const int*   edge_idx = (const int*)d_in[3];
    float* out = (float*)d_out;

    // workspace carve-up
    unsigned* ebkt = (unsigned*)d_ws;                    // NNZ
    unsigned* nbkt = ebkt + NNZ;                         // NNZ
    int* e_nodes = (int*)(nbkt + NNZ);                   // NNZ
    int* n_edges = e_nodes + NNZ;                        // NNZ
    int* e_off   = n_edges + NNZ;                        // N_EDGES+1
    int* n_off   = e_off + (N_EDGES + 1);                // N_NODES+1
    int* ebcnt   = n_off + (N_NODES + 1);                // 200 (pad)
    int* nbcnt   = ebcnt + 200;                          // 200
    int* ebOff   = nbcnt + 200;                          // 200
    int* nbOff   = ebOff + 200;                          // 200
    int* ebCur   = nbOff + 200;                          // 200
    int* nbCur   = ebCur + 200;                          // 200
    float* probs = (float*)(nbCur + 200);                // N_NODES*K (8B-aligned: even int offset)
    float* edge_feat = (float*)ebkt;                     // N_EDGES*K, aliases dead bucket arrays

    hipMemsetAsync(ebcnt, 0, 400 * sizeof(int), stream);

    bhist_k<<<1024, 256, 0, stream>>>(node_idx, edge_idx, ebcnt, nbcnt);
    bscan_k<<<1, 512, 0, stream>>>(ebcnt, nbcnt, ebOff, nbOff, ebCur, nbCur, e_off, n_off);
    bpart_k<<<(NNZ + 2047) / 2048, 256, 0, stream>>>(node_idx, edge_idx, ebCur, nbCur, ebkt, nbkt);
    bfill_k<<<NB_E + NB_N, 256, 0, stream>>>(ebkt, nbkt, ebOff, nbOff, e_off, n_off, e_nodes, n_edges);

    softmax_k<<<(N_NODES + 3) / 4, 256, 0, stream>>>(y, probs);
    mm2_k<<<(N_EDGES + 15) / 16, 256, 0, stream>>>(probs, e_off, e_nodes, W, edge_feat);
    node_fin_k<<<(N_NODES + 3) / 4, 256, 0, stream>>>(probs, n_off, n_edges, edge_feat, out);
}

// Round 4
// 305.787 us; speedup vs baseline: 5.1033x; 1.2912x over previous
//
#include <hip/hip_runtime.h>
#include <hip/hip_fp16.h>

#define N_NODES 100000
#define N_EDGES 25000
#define K 128
#define NNZ 1600000

// edge buckets: 128 edges each; node buckets: 512 nodes each
#define NB_E 196   // ceil(25000/128)
#define NB_N 196   // ceil(100000/512)
// packed entry: (edge << 17) | node   (edge < 2^15, node < 2^17)

// -------- softmax over rows of y -> probs (fp16 out, f32 math) --------
__global__ __launch_bounds__(256) void softmax_k(const float* __restrict__ y,
                                                 __half2* __restrict__ probs_h) {
    int wid = threadIdx.x >> 6, lane = threadIdx.x & 63;
    int row = blockIdx.x * 4 + wid;
    if (row >= N_NODES) return;
    const float2* yr = (const float2*)(y + (size_t)row * K);
    float2 a = yr[lane];
    float m = fmaxf(a.x, a.y);
    #pragma unroll
    for (int off = 32; off >= 1; off >>= 1) m = fmaxf(m, __shfl_xor(m, off, 64));
    float e0 = expf(a.x - m);
    float e1 = expf(a.y - m);
    float s = e0 + e1;
    #pragma unroll
    for (int off = 32; off >= 1; off >>= 1) s += __shfl_xor(s, off, 64);
    float inv = 1.0f / s;
    probs_h[(size_t)row * 64 + lane] = __floats2half2_rn(e0 * inv, e1 * inv);
}

// ---------------- bucket histogram (both sides) ----------------
__global__ __launch_bounds__(256) void bhist_k(const int* __restrict__ ni,
                                               const int* __restrict__ ei,
                                               int* __restrict__ ebcnt,
                                               int* __restrict__ nbcnt) {
    __shared__ int se[NB_E], sn[NB_N];
    for (int t = threadIdx.x; t < NB_E; t += 256) se[t] = 0;
    for (int t = threadIdx.x; t < NB_N; t += 256) sn[t] = 0;
    __syncthreads();
    for (int i = blockIdx.x * 256 + threadIdx.x; i < NNZ; i += gridDim.x * 256) {
        atomicAdd(&se[ei[i] >> 7], 1);
        atomicAdd(&sn[ni[i] >> 9], 1);
    }
    __syncthreads();
    for (int t = threadIdx.x; t < NB_E; t += 256) if (se[t]) atomicAdd(&ebcnt[t], se[t]);
    for (int t = threadIdx.x; t < NB_N; t += 256) if (sn[t]) atomicAdd(&nbcnt[t], sn[t]);
}

// ---------------- scan bucket counts -> offsets + cursors ----------------
__global__ __launch_bounds__(512) void bscan_k(const int* __restrict__ ebcnt,
                                               const int* __restrict__ nbcnt,
                                               int* __restrict__ ebOff, int* __restrict__ nbOff,
                                               int* __restrict__ ebCur, int* __restrict__ nbCur,
                                               int* __restrict__ e_off, int* __restrict__ n_off) {
    __shared__ int s[512];
    int t = threadIdx.x;
    int half = t >> 8, idx = t & 255;
    int v = 0;
    if (half == 0) v = (idx < NB_E) ? ebcnt[idx] : 0;
    else           v = (idx < NB_N) ? nbcnt[idx] : 0;
    s[t] = v;
    __syncthreads();
    for (int d = 1; d < 256; d <<= 1) {
        int add = (idx >= d) ? s[t - d] : 0;
        __syncthreads();
        s[t] += add;
        __syncthreads();
    }
    int excl = s[t] - v;
    if (half == 0 && idx < NB_E) {
        ebOff[idx] = excl; ebCur[idx] = excl;
        if (idx == NB_E - 1) ebOff[NB_E] = excl + v;
    }
    if (half == 1 && idx < NB_N) {
        nbOff[idx] = excl; nbCur[idx] = excl;
        if (idx == NB_N - 1) nbOff[NB_N] = excl + v;
    }
    if (t == 0) { e_off[N_EDGES] = NNZ; n_off[N_NODES] = NNZ; }
}

// ---------------- partition entries into buckets (both sides) ----------------
__global__ __launch_bounds__(256) void bpart_k(const int* __restrict__ ni,
                                               const int* __restrict__ ei,
                                               int* __restrict__ ebCur, int* __restrict__ nbCur,
                                               unsigned* __restrict__ ebkt,
                                               unsigned* __restrict__ nbkt) {
    __shared__ int cnt[NB_E > NB_N ? NB_E : NB_N];
    __shared__ int runb[NB_E > NB_N ? NB_E : NB_N];
    unsigned pk[8]; int rk[8]; bool val[8];
    int i0 = blockIdx.x * 2048;
    #pragma unroll
    for (int k = 0; k < 8; ++k) {
        int i = i0 + threadIdx.x + k * 256;
        val[k] = (i < NNZ);
        pk[k] = val[k] ? (((unsigned)ei[i] << 17) | (unsigned)ni[i]) : 0u;
    }
    // ---- edge side: bucket = pk >> 24 ----
    for (int t = threadIdx.x; t < NB_E; t += 256) cnt[t] = 0;
    __syncthreads();
    #pragma unroll
    for (int k = 0; k < 8; ++k) if (val[k]) rk[k] = atomicAdd(&cnt[pk[k] >> 24], 1);
    __syncthreads();
    for (int t = threadIdx.x; t < NB_E; t += 256)
        runb[t] = cnt[t] ? atomicAdd(&ebCur[t], cnt[t]) : 0;
    __syncthreads();
    #pragma unroll
    for (int k = 0; k < 8; ++k) if (val[k]) ebkt[runb[pk[k] >> 24] + rk[k]] = pk[k];
    __syncthreads();
    // ---- node side: bucket = (pk >> 9) & 0xFF ----
    for (int t = threadIdx.x; t < NB_N; t += 256) cnt[t] = 0;
    __syncthreads();
    #pragma unroll
    for (int k = 0; k < 8; ++k) if (val[k]) rk[k] = atomicAdd(&cnt[(pk[k] >> 9) & 0xFF], 1);
    __syncthreads();
    for (int t = threadIdx.x; t < NB_N; t += 256)
        runb[t] = cnt[t] ? atomicAdd(&nbCur[t], cnt[t]) : 0;
    __syncthreads();
    #pragma unroll
    for (int k = 0; k < 8; ++k) if (val[k]) nbkt[runb[(pk[k] >> 9) & 0xFF] + rk[k]] = pk[k];
}

// ------- per-bucket: counts -> local scan -> csr offsets + ranked fill -------
__global__ __launch_bounds__(256) void bfill_k(const unsigned* __restrict__ ebkt,
                                               const unsigned* __restrict__ nbkt,
                                               const int* __restrict__ ebOff,
                                               const int* __restrict__ nbOff,
                                               int* __restrict__ e_off, int* __restrict__ n_off,
                                               int* __restrict__ e_nodes,
                                               int* __restrict__ n_edges) {
    __shared__ int cnt[512];
    __shared__ int par[256];
    int b = blockIdx.x;
    int t = threadIdx.x;
    if (b < NB_E) {
        int beg = ebOff[b], end = ebOff[b + 1];
        for (int x = t; x < 128; x += 256) cnt[x] = 0;
        __syncthreads();
        int i = beg + t;
        for (; i + 768 < end; i += 1024) {
            unsigned p0 = ebkt[i], p1 = ebkt[i + 256], p2 = ebkt[i + 512], p3 = ebkt[i + 768];
            atomicAdd(&cnt[(p0 >> 17) & 127], 1);
            atomicAdd(&cnt[(p1 >> 17) & 127], 1);
            atomicAdd(&cnt[(p2 >> 17) & 127], 1);
            atomicAdd(&cnt[(p3 >> 17) & 127], 1);
        }
        for (; i < end; i += 256) atomicAdd(&cnt[(ebkt[i] >> 17) & 127], 1);
        __syncthreads();
        int v = (t < 128) ? cnt[t] : 0;
        par[t] = v;
        __syncthreads();
        for (int d = 1; d < 256; d <<= 1) {
            int add = (t >= d) ? par[t - d] : 0;
            __syncthreads();
            par[t] += add;
            __syncthreads();
        }
        if (t < 128) {
            int excl = par[t] - v;
            cnt[t] = excl;
            int e = (b << 7) + t;
            if (e < N_EDGES) e_off[e] = beg + excl;
        }
        __syncthreads();
        i = beg + t;
        for (; i + 768 < end; i += 1024) {
            unsigned p0 = ebkt[i], p1 = ebkt[i + 256], p2 = ebkt[i + 512], p3 = ebkt[i + 768];
            int d0 = atomicAdd(&cnt[(p0 >> 17) & 127], 1);
            int d1 = atomicAdd(&cnt[(p1 >> 17) & 127], 1);
            int d2 = atomicAdd(&cnt[(p2 >> 17) & 127], 1);
            int d3 = atomicAdd(&cnt[(p3 >> 17) & 127], 1);
            e_nodes[beg + d0] = p0 & 0x1FFFF;
            e_nodes[beg + d1] = p1 & 0x1FFFF;
            e_nodes[beg + d2] = p2 & 0x1FFFF;
            e_nodes[beg + d3] = p3 & 0x1FFFF;
        }
        for (; i < end; i += 256) {
            unsigned p = ebkt[i];
            int d = atomicAdd(&cnt[(p >> 17) & 127], 1);
            e_nodes[beg + d] = p & 0x1FFFF;
        }
    } else {
        int b2 = b - NB_E;
        int beg = nbOff[b2], end = nbOff[b2 + 1];
        for (int x = t; x < 512; x += 256) cnt[x] = 0;
        __syncthreads();
        int i = beg + t;
        for (; i + 768 < end; i += 1024) {
            unsigned p0 = nbkt[i], p1 = nbkt[i + 256], p2 = nbkt[i + 512], p3 = nbkt[i + 768];
            atomicAdd(&cnt[p0 & 511], 1);
            atomicAdd(&cnt[p1 & 511], 1);
            atomicAdd(&cnt[p2 & 511], 1);
            atomicAdd(&cnt[p3 & 511], 1);
        }
        for (; i < end; i += 256) atomicAdd(&cnt[nbkt[i] & 511], 1);
        __syncthreads();
        int v0 = cnt[t * 2], v1 = cnt[t * 2 + 1];
        int vs = v0 + v1;
        par[t] = vs;
        __syncthreads();
        for (int d = 1; d < 256; d <<= 1) {
            int add = (t >= d) ? par[t - d] : 0;
            __syncthreads();
            par[t] += add;
            __syncthreads();
        }
        int excl = par[t] - vs;
        __syncthreads();
        cnt[t * 2] = excl;
        cnt[t * 2 + 1] = excl + v0;
        int n = (b2 << 9) + t * 2;
        if (n < N_NODES)     n_off[n]     = beg + excl;
        if (n + 1 < N_NODES) n_off[n + 1] = beg + excl + v0;
        __syncthreads();
        i = beg + t;
        for (; i + 768 < end; i += 1024) {
            unsigned p0 = nbkt[i], p1 = nbkt[i + 256], p2 = nbkt[i + 512], p3 = nbkt[i + 768];
            int d0 = atomicAdd(&cnt[p0 & 511], 1);
            int d1 = atomicAdd(&cnt[p1 & 511], 1);
            int d2 = atomicAdd(&cnt[p2 & 511], 1);
            int d3 = atomicAdd(&cnt[p3 & 511], 1);
            n_edges[beg + d0] = p0 >> 17;
            n_edges[beg + d1] = p1 >> 17;
            n_edges[beg + d2] = p2 >> 17;
            n_edges[beg + d3] = p3 >> 17;
        }
        for (; i < end; i += 256) {
            unsigned p = nbkt[i];
            int d = atomicAdd(&cnt[p & 511], 1);
            n_edges[beg + d] = p >> 17;
        }
    }
}

// ------- fused: gather probs(fp16) -> edge mean (LDS f32) -> @W -> edge_feat(fp16) -------
__global__ __launch_bounds__(256) void mm2_k(const __half2* __restrict__ probs_h,
                                             const int* __restrict__ e_off,
                                             const int* __restrict__ e_nodes,
                                             const float* __restrict__ W,
                                             __half* __restrict__ edge_feat_h) {
    __shared__ float a_s[16][K];
    int row0 = blockIdx.x * 16;
    int wid = threadIdx.x >> 6, lane = threadIdx.x & 63;

    for (int rr = 0; rr < 4; ++rr) {
        int e = row0 + wid * 4 + rr;
        float ax = 0.f, ay = 0.f, bx = 0.f, by = 0.f, cx = 0.f, cy = 0.f, dx = 0.f, dy = 0.f;
        if (e < N_EDGES) {
            int beg = e_off[e], end = e_off[e + 1];
            int j = beg;
            for (; j + 3 < end; j += 4) {
                int h0 = e_nodes[j], h1 = e_nodes[j + 1];
                int h2 = e_nodes[j + 2], h3 = e_nodes[j + 3];
                float2 q0 = __half22float2(probs_h[(size_t)h0 * 64 + lane]);
                float2 q1 = __half22float2(probs_h[(size_t)h1 * 64 + lane]);
                float2 q2 = __half22float2(probs_h[(size_t)h2 * 64 + lane]);
                float2 q3 = __half22float2(probs_h[(size_t)h3 * 64 + lane]);
                ax += q0.x; ay += q0.y; bx += q1.x; by += q1.y;
                cx += q2.x; cy += q2.y; dx += q3.x; dy += q3.y;
            }
            for (; j < end; ++j) {
                float2 q = __half22float2(probs_h[(size_t)e_nodes[j] * 64 + lane]);
                ax += q.x; ay += q.y;
            }
            float inv = 1.0f / fmaxf((float)(end - beg), 1.0f);
            ax = (ax + bx + cx + dx) * inv;
            ay = (ay + by + cy + dy) * inv;
        }
        *(float2*)(&a_s[wid * 4 + rr][2 * lane]) = make_float2(ax, ay);
    }
    __syncthreads();

    int jcol = threadIdx.x & 127;
    int rg = threadIdx.x >> 7;
    float acc[8];
    #pragma unroll
    for (int r = 0; r < 8; ++r) acc[r] = 0.0f;
    for (int k = 0; k < K; ++k) {
        float w = W[k * K + jcol];
        #pragma unroll
        for (int r = 0; r < 8; ++r) acc[r] = fmaf(a_s[rg * 8 + r][k], w, acc[r]);
    }
    #pragma unroll
    for (int r = 0; r < 8; ++r) {
        int row = row0 + rg * 8 + r;
        if (row < N_EDGES) edge_feat_h[(size_t)row * K + jcol] = __float2half(acc[r]);
    }
}

// ------- fused: gather edge_feat(fp16) -> node mean; nat-grad; mean-center -------
__global__ __launch_bounds__(256) void node_fin_k(const __half2* __restrict__ probs_h,
                                                  const int* __restrict__ n_off,
                                                  const int* __restrict__ n_edges,
                                                  const __half2* __restrict__ edge_feat_h,
                                                  float* __restrict__ out) {
    int wid = threadIdx.x >> 6, lane = threadIdx.x & 63;
    int row = blockIdx.x * 4 + wid;
    if (row >= N_NODES) return;
    int beg = n_off[row], end = n_off[row + 1];
    float ax = 0.f, ay = 0.f, bx = 0.f, by = 0.f, cx = 0.f, cy = 0.f, dx = 0.f, dy = 0.f;
    int j = beg;
    for (; j + 3 < end; j += 4) {
        int h0 = n_edges[j], h1 = n_edges[j + 1];
        int h2 = n_edges[j + 2], h3 = n_edges[j + 3];
        float2 q0 = __half22float2(edge_feat_h[(size_t)h0 * 64 + lane]);
        float2 q1 = __half22float2(edge_feat_h[(size_t)h1 * 64 + lane]);
        float2 q2 = __half22float2(edge_feat_h[(size_t)h2 * 64 + lane]);
        float2 q3 = __half22float2(edge_feat_h[(size_t)h3 * 64 + lane]);
        ax += q0.x; ay += q0.y; bx += q1.x; by += q1.y;
        cx += q2.x; cy += q2.y; dx += q3.x; dy += q3.y;
    }
    for (; j < end; ++j) {
        float2 q = __half22float2(edge_feat_h[(size_t)n_edges[j] * 64 + lane]);
        ax += q.x; ay += q.y;
    }
    float inv = 1.0f / fmaxf((float)(end - beg), 1.0f);
    float2 p = __half22float2(probs_h[(size_t)row * 64 + lane]);
    float v0 = fmaxf(p.x, 1e-12f) * ((ax + bx + cx + dx) * inv);
    float v1 = fmaxf(p.y, 1e-12f) * ((ay + by + cy + dy) * inv);
    float s = v0 + v1;
    #pragma unroll
    for (int off = 32; off >= 1; off >>= 1) s += __shfl_xor(s, off, 64);
    float mean = s * (1.0f / (float)K);
    *(float2*)(out + (size_t)row * K + 2 * lane) = make_float2(v0 - mean, v1 - mean);
}

extern "C" void kernel_launch(void* const* d_in, const int* in_sizes, int n_in,
                              void* d_out, int out_size, void* d_ws, size_t ws_size,
                              hipStream_t stream) {
    const float* y        = (const float*)d_in[0];
    const float* W        = (const float*)d_in[1];
    const int*   node_idx = (const int*)d_in[2];
    const int*   edge_idx = (const int*)d_in[3];
    float* out = (float*)d_out;

    // workspace carve-up (4-byte units unless noted)
    unsigned* ebkt = (unsigned*)d_ws;                    // NNZ
    unsigned* nbkt = ebkt + NNZ;                         // NNZ
    int* e_nodes = (int*)(nbkt + NNZ);                   // NNZ
    int* n_edges = e_nodes + NNZ;                        // NNZ
    int* e_off   = n_edges + NNZ;                        // N_EDGES+1
    int* n_off   = e_off + (N_EDGES + 1);                // N_NODES+1
    int* ebcnt   = n_off + (N_NODES + 1);                // 200 (pad)
    int* nbcnt   = ebcnt + 200;                          // 200
    int* ebOff   = nbcnt + 200;                          // 200
    int* nbOff   = ebOff + 200;                          // 200
    int* ebCur   = nbOff + 200;                          // 200
    int* nbCur   = ebCur + 200;                          // 200
    __half2* probs_h = (__half2*)(nbCur + 200);          // N_NODES*64 half2 = 25.6 MB
    __half*  edge_feat_h = (__half*)ebkt;                // N_EDGES*K halves, aliases dead ebkt

    hipMemsetAsync(ebcnt, 0, 400 * sizeof(int), stream);

    bhist_k<<<1024, 256, 0, stream>>>(node_idx, edge_idx, ebcnt, nbcnt);
    bscan_k<<<1, 512, 0, stream>>>(ebcnt, nbcnt, ebOff, nbOff, ebCur, nbCur, e_off, n_off);
    bpart_k<<<(NNZ + 2047) / 2048, 256, 0, stream>>>(node_idx, edge_idx, ebCur, nbCur, ebkt, nbkt);
    bfill_k<<<NB_E + NB_N, 256, 0, stream>>>(ebkt, nbkt, ebOff, nbOff, e_off, n_off, e_nodes, n_edges);

    softmax_k<<<(N_NODES + 3) / 4, 256, 0, stream>>>(y, probs_h);
    mm2_k<<<(N_EDGES + 15) / 16, 256, 0, stream>>>(probs_h, e_off, e_nodes, W, edge_feat_h);
    node_fin_k<<<(N_NODES + 3) / 4, 256, 0, stream>>>(probs_h, n_off, n_edges,
                                                      (const __half2*)edge_feat_h, out);
}

// Round 5
// 287.622 us; speedup vs baseline: 5.4256x; 1.0632x over previous
//
#include <hip/hip_runtime.h>
#include <hip/hip_fp16.h>

#define N_NODES 100000
#define N_EDGES 25000
#define K 128
#define NNZ 1600000

// edge buckets: 128 edges each; node buckets: 512 nodes each
#define NB_E 196   // ceil(25000/128)
#define NB_N 196   // ceil(100000/512)
// packed entry: (edge << 17) | node   (edge < 2^15, node < 2^17)

// -------- softmax over rows of y -> probs (fp16 out, f32 math) --------
__global__ __launch_bounds__(256) void softmax_k(const float* __restrict__ y,
                                                 __half2* __restrict__ probs_h) {
    int wid = threadIdx.x >> 6, lane = threadIdx.x & 63;
    int row = blockIdx.x * 4 + wid;
    if (row >= N_NODES) return;
    const float2* yr = (const float2*)(y + (size_t)row * K);
    float2 a = yr[lane];
    float m = fmaxf(a.x, a.y);
    #pragma unroll
    for (int off = 32; off >= 1; off >>= 1) m = fmaxf(m, __shfl_xor(m, off, 64));
    float e0 = expf(a.x - m);
    float e1 = expf(a.y - m);
    float s = e0 + e1;
    #pragma unroll
    for (int off = 32; off >= 1; off >>= 1) s += __shfl_xor(s, off, 64);
    float inv = 1.0f / s;
    probs_h[(size_t)row * 64 + lane] = __floats2half2_rn(e0 * inv, e1 * inv);
}

// ---------------- bucket histogram (both sides) ----------------
__global__ __launch_bounds__(256) void bhist_k(const int* __restrict__ ni,
                                               const int* __restrict__ ei,
                                               int* __restrict__ ebcnt,
                                               int* __restrict__ nbcnt) {
    __shared__ int se[NB_E], sn[NB_N];
    for (int t = threadIdx.x; t < NB_E; t += 256) se[t] = 0;
    for (int t = threadIdx.x; t < NB_N; t += 256) sn[t] = 0;
    __syncthreads();
    for (int i = blockIdx.x * 256 + threadIdx.x; i < NNZ; i += gridDim.x * 256) {
        atomicAdd(&se[ei[i] >> 7], 1);
        atomicAdd(&sn[ni[i] >> 9], 1);
    }
    __syncthreads();
    for (int t = threadIdx.x; t < NB_E; t += 256) if (se[t]) atomicAdd(&ebcnt[t], se[t]);
    for (int t = threadIdx.x; t < NB_N; t += 256) if (sn[t]) atomicAdd(&nbcnt[t], sn[t]);
}

// ---------------- scan bucket counts -> offsets + cursors ----------------
__global__ __launch_bounds__(512) void bscan_k(const int* __restrict__ ebcnt,
                                               const int* __restrict__ nbcnt,
                                               int* __restrict__ ebOff, int* __restrict__ nbOff,
                                               int* __restrict__ ebCur, int* __restrict__ nbCur,
                                               int* __restrict__ e_off, int* __restrict__ n_off) {
    __shared__ int s[512];
    int t = threadIdx.x;
    int half = t >> 8, idx = t & 255;
    int v = 0;
    if (half == 0) v = (idx < NB_E) ? ebcnt[idx] : 0;
    else           v = (idx < NB_N) ? nbcnt[idx] : 0;
    s[t] = v;
    __syncthreads();
    for (int d = 1; d < 256; d <<= 1) {
        int add = (idx >= d) ? s[t - d] : 0;
        __syncthreads();
        s[t] += add;
        __syncthreads();
    }
    int excl = s[t] - v;
    if (half == 0 && idx < NB_E) {
        ebOff[idx] = excl; ebCur[idx] = excl;
        if (idx == NB_E - 1) ebOff[NB_E] = excl + v;
    }
    if (half == 1 && idx < NB_N) {
        nbOff[idx] = excl; nbCur[idx] = excl;
        if (idx == NB_N - 1) nbOff[NB_N] = excl + v;
    }
    if (t == 0) { e_off[N_EDGES] = NNZ; n_off[N_NODES] = NNZ; }
}

// ---------------- partition entries into buckets (both sides) ----------------
__global__ __launch_bounds__(256) void bpart_k(const int* __restrict__ ni,
                                               const int* __restrict__ ei,
                                               int* __restrict__ ebCur, int* __restrict__ nbCur,
                                               unsigned* __restrict__ ebkt,
                                               unsigned* __restrict__ nbkt) {
    __shared__ int cnt[NB_E > NB_N ? NB_E : NB_N];
    __shared__ int runb[NB_E > NB_N ? NB_E : NB_N];
    unsigned pk[8]; int rk[8]; bool val[8];
    int i0 = blockIdx.x * 2048;
    #pragma unroll
    for (int k = 0; k < 8; ++k) {
        int i = i0 + threadIdx.x + k * 256;
        val[k] = (i < NNZ);
        pk[k] = val[k] ? (((unsigned)ei[i] << 17) | (unsigned)ni[i]) : 0u;
    }
    // ---- edge side: bucket = pk >> 24 ----
    for (int t = threadIdx.x; t < NB_E; t += 256) cnt[t] = 0;
    __syncthreads();
    #pragma unroll
    for (int k = 0; k < 8; ++k) if (val[k]) rk[k] = atomicAdd(&cnt[pk[k] >> 24], 1);
    __syncthreads();
    for (int t = threadIdx.x; t < NB_E; t += 256)
        runb[t] = cnt[t] ? atomicAdd(&ebCur[t], cnt[t]) : 0;
    __syncthreads();
    #pragma unroll
    for (int k = 0; k < 8; ++k) if (val[k]) ebkt[runb[pk[k] >> 24] + rk[k]] = pk[k];
    __syncthreads();
    // ---- node side: bucket = (pk >> 9) & 0xFF ----
    for (int t = threadIdx.x; t < NB_N; t += 256) cnt[t] = 0;
    __syncthreads();
    #pragma unroll
    for (int k = 0; k < 8; ++k) if (val[k]) rk[k] = atomicAdd(&cnt[(pk[k] >> 9) & 0xFF], 1);
    __syncthreads();
    for (int t = threadIdx.x; t < NB_N; t += 256)
        runb[t] = cnt[t] ? atomicAdd(&nbCur[t], cnt[t]) : 0;
    __syncthreads();
    #pragma unroll
    for (int k = 0; k < 8; ++k) if (val[k]) nbkt[runb[(pk[k] >> 9) & 0xFF] + rk[k]] = pk[k];
}

// ------- per-bucket: counts -> local scan -> csr offsets + ranked fill -------
__global__ __launch_bounds__(256) void bfill_k(const unsigned* __restrict__ ebkt,
                                               const unsigned* __restrict__ nbkt,
                                               const int* __restrict__ ebOff,
                                               const int* __restrict__ nbOff,
                                               int* __restrict__ e_off, int* __restrict__ n_off,
                                               int* __restrict__ e_nodes,
                                               int* __restrict__ n_edges) {
    __shared__ int cnt[512];
    __shared__ int par[256];
    int b = blockIdx.x;
    int t = threadIdx.x;
    if (b < NB_E) {
        int beg = ebOff[b], end = ebOff[b + 1];
        for (int x = t; x < 128; x += 256) cnt[x] = 0;
        __syncthreads();
        int i = beg + t;
        for (; i + 768 < end; i += 1024) {
            unsigned p0 = ebkt[i], p1 = ebkt[i + 256], p2 = ebkt[i + 512], p3 = ebkt[i + 768];
            atomicAdd(&cnt[(p0 >> 17) & 127], 1);
            atomicAdd(&cnt[(p1 >> 17) & 127], 1);
            atomicAdd(&cnt[(p2 >> 17) & 127], 1);
            atomicAdd(&cnt[(p3 >> 17) & 127], 1);
        }
        for (; i < end; i += 256) atomicAdd(&cnt[(ebkt[i] >> 17) & 127], 1);
        __syncthreads();
        int v = (t < 128) ? cnt[t] : 0;
        par[t] = v;
        __syncthreads();
        for (int d = 1; d < 256; d <<= 1) {
            int add = (t >= d) ? par[t - d] : 0;
            __syncthreads();
            par[t] += add;
            __syncthreads();
        }
        if (t < 128) {
            int excl = par[t] - v;
            cnt[t] = excl;
            int e = (b << 7) + t;
            if (e < N_EDGES) e_off[e] = beg + excl;
        }
        __syncthreads();
        i = beg + t;
        for (; i + 768 < end; i += 1024) {
            unsigned p0 = ebkt[i], p1 = ebkt[i + 256], p2 = ebkt[i + 512], p3 = ebkt[i + 768];
            int d0 = atomicAdd(&cnt[(p0 >> 17) & 127], 1);
            int d1 = atomicAdd(&cnt[(p1 >> 17) & 127], 1);
            int d2 = atomicAdd(&cnt[(p2 >> 17) & 127], 1);
            int d3 = atomicAdd(&cnt[(p3 >> 17) & 127], 1);
            e_nodes[beg + d0] = p0 & 0x1FFFF;
            e_nodes[beg + d1] = p1 & 0x1FFFF;
            e_nodes[beg + d2] = p2 & 0x1FFFF;
            e_nodes[beg + d3] = p3 & 0x1FFFF;
        }
        for (; i < end; i += 256) {
            unsigned p = ebkt[i];
            int d = atomicAdd(&cnt[(p >> 17) & 127], 1);
            e_nodes[beg + d] = p & 0x1FFFF;
        }
    } else {
        int b2 = b - NB_E;
        int beg = nbOff[b2], end = nbOff[b2 + 1];
        for (int x = t; x < 512; x += 256) cnt[x] = 0;
        __syncthreads();
        int i = beg + t;
        for (; i + 768 < end; i += 1024) {
            unsigned p0 = nbkt[i], p1 = nbkt[i + 256], p2 = nbkt[i + 512], p3 = nbkt[i + 768];
            atomicAdd(&cnt[p0 & 511], 1);
            atomicAdd(&cnt[p1 & 511], 1);
            atomicAdd(&cnt[p2 & 511], 1);
            atomicAdd(&cnt[p3 & 511], 1);
        }
        for (; i < end; i += 256) atomicAdd(&cnt[nbkt[i] & 511], 1);
        __syncthreads();
        int v0 = cnt[t * 2], v1 = cnt[t * 2 + 1];
        int vs = v0 + v1;
        par[t] = vs;
        __syncthreads();
        for (int d = 1; d < 256; d <<= 1) {
            int add = (t >= d) ? par[t - d] : 0;
            __syncthreads();
            par[t] += add;
            __syncthreads();
        }
        int excl = par[t] - vs;
        __syncthreads();
        cnt[t * 2] = excl;
        cnt[t * 2 + 1] = excl + v0;
        int n = (b2 << 9) + t * 2;
        if (n < N_NODES)     n_off[n]     = beg + excl;
        if (n + 1 < N_NODES) n_off[n + 1] = beg + excl + v0;
        __syncthreads();
        i = beg + t;
        for (; i + 768 < end; i += 1024) {
            unsigned p0 = nbkt[i], p1 = nbkt[i + 256], p2 = nbkt[i + 512], p3 = nbkt[i + 768];
            int d0 = atomicAdd(&cnt[p0 & 511], 1);
            int d1 = atomicAdd(&cnt[p1 & 511], 1);
            int d2 = atomicAdd(&cnt[p2 & 511], 1);
            int d3 = atomicAdd(&cnt[p3 & 511], 1);
            n_edges[beg + d0] = p0 >> 17;
            n_edges[beg + d1] = p1 >> 17;
            n_edges[beg + d2] = p2 >> 17;
            n_edges[beg + d3] = p3 >> 17;
        }
        for (; i < end; i += 256) {
            unsigned p = nbkt[i];
            int d = atomicAdd(&cnt[p & 511], 1);
            n_edges[beg + d] = p >> 17;
        }
    }
}

// ------- fused: gather probs(fp16, 16 lanes/row) -> edge mean -> @W -> edge_feat(fp16) -------
// 256 threads = 4 waves; block owns 16 edges; wave w owns edges w*4..w*4+3.
// Gather: lane-group g=lane>>4 handles entry j+g; each lane loads 16B (8 halves).
__global__ __launch_bounds__(256) void mm2_k(const __half2* __restrict__ probs_h,
                                             const int* __restrict__ e_off,
                                             const int* __restrict__ e_nodes,
                                             const float* __restrict__ W,
                                             __half* __restrict__ edge_feat_h) {
    __shared__ float a_s[16][K];
    int wid = threadIdx.x >> 6, lane = threadIdx.x & 63;
    int g = lane >> 4, li = lane & 15;
    const uint4* pr4 = (const uint4*)probs_h;      // 16 uint4 per 256B row

    for (int rr = 0; rr < 4; ++rr) {
        int e = blockIdx.x * 16 + wid * 4 + rr;
        int beg = 0, end = 0;
        if (e < N_EDGES) { beg = e_off[e]; end = e_off[e + 1]; }
        float2 a0 = {0.f, 0.f}, a1 = {0.f, 0.f}, a2 = {0.f, 0.f}, a3 = {0.f, 0.f};
        #pragma unroll 2
        for (int j = beg; j < end; j += 4) {
            int jj = j + g;
            if (jj < end) {
                int idx = e_nodes[jj];
                uint4 q = pr4[(size_t)idx * 16 + li];
                float2 f0 = __half22float2(*(__half2*)&q.x);
                float2 f1 = __half22float2(*(__half2*)&q.y);
                float2 f2 = __half22float2(*(__half2*)&q.z);
                float2 f3 = __half22float2(*(__half2*)&q.w);
                a0.x += f0.x; a0.y += f0.y; a1.x += f1.x; a1.y += f1.y;
                a2.x += f2.x; a2.y += f2.y; a3.x += f3.x; a3.y += f3.y;
            }
        }
        // combine the 4 lane-groups (each lane ends with the full sum for its 8 cols)
        #pragma unroll
        for (int off = 16; off <= 32; off <<= 1) {
            a0.x += __shfl_xor(a0.x, off, 64); a0.y += __shfl_xor(a0.y, off, 64);
            a1.x += __shfl_xor(a1.x, off, 64); a1.y += __shfl_xor(a1.y, off, 64);
            a2.x += __shfl_xor(a2.x, off, 64); a2.y += __shfl_xor(a2.y, off, 64);
            a3.x += __shfl_xor(a3.x, off, 64); a3.y += __shfl_xor(a3.y, off, 64);
        }
        float inv = 1.0f / fmaxf((float)(end - beg), 1.0f);
        if (g == 0) {
            float* as = &a_s[wid * 4 + rr][li * 8];
            *(float4*)as       = make_float4(a0.x * inv, a0.y * inv, a1.x * inv, a1.y * inv);
            *(float4*)(as + 4) = make_float4(a2.x * inv, a2.y * inv, a3.x * inv, a3.y * inv);
        }
    }
    __syncthreads();

    // GEMM: thread (rq = tid>>6, jp = tid&63) computes rows rq*4..+3, cols jp*2,jp*2+1
    int rq = threadIdx.x >> 6;
    int jp = threadIdx.x & 63;
    float2 c0 = {0.f, 0.f}, c1 = {0.f, 0.f}, c2 = {0.f, 0.f}, c3 = {0.f, 0.f};
    for (int k = 0; k < K; k += 4) {
        float4 b0 = *(float4*)&a_s[rq * 4 + 0][k];
        float4 b1 = *(float4*)&a_s[rq * 4 + 1][k];
        float4 b2 = *(float4*)&a_s[rq * 4 + 2][k];
        float4 b3 = *(float4*)&a_s[rq * 4 + 3][k];
        float2 w0 = *(const float2*)&W[(k + 0) * K + jp * 2];
        float2 w1 = *(const float2*)&W[(k + 1) * K + jp * 2];
        float2 w2 = *(const float2*)&W[(k + 2) * K + jp * 2];
        float2 w3 = *(const float2*)&W[(k + 3) * K + jp * 2];
        c0.x += b0.x * w0.x + b0.y * w1.x + b0.z * w2.x + b0.w * w3.x;
        c0.y += b0.x * w0.y + b0.y * w1.y + b0.z * w2.y + b0.w * w3.y;
        c1.x += b1.x * w0.x + b1.y * w1.x + b1.z * w2.x + b1.w * w3.x;
        c1.y += b1.x * w0.y + b1.y * w1.y + b1.z * w2.y + b1.w * w3.y;
        c2.x += b2.x * w0.x + b2.y * w1.x + b2.z * w2.x + b2.w * w3.x;
        c2.y += b2.x * w0.y + b2.y * w1.y + b2.z * w2.y + b2.w * w3.y;
        c3.x += b3.x * w0.x + b3.y * w1.x + b3.z * w2.x + b3.w * w3.x;
        c3.y += b3.x * w0.y + b3.y * w1.y + b3.z * w2.y + b3.w * w3.y;
    }
    __half2* ef2 = (__half2*)edge_feat_h;
    int r0 = blockIdx.x * 16 + rq * 4;
    if (r0 + 0 < N_EDGES) ef2[(size_t)(r0 + 0) * 64 + jp] = __floats2half2_rn(c0.x, c0.y);
    if (r0 + 1 < N_EDGES) ef2[(size_t)(r0 + 1) * 64 + jp] = __floats2half2_rn(c1.x, c1.y);
    if (r0 + 2 < N_EDGES) ef2[(size_t)(r0 + 2) * 64 + jp] = __floats2half2_rn(c2.x, c2.y);
    if (r0 + 3 < N_EDGES) ef2[(size_t)(r0 + 3) * 64 + jp] = __floats2half2_rn(c3.x, c3.y);
}

// ------- fused: gather edge_feat(fp16) -> node mean; nat-grad; mean-center -------
// 256 threads = 4 waves; block owns 16 nodes; wave owns 4 (lane-group g per node).
__global__ __launch_bounds__(256) void node_fin_k(const __half2* __restrict__ probs_h,
                                                  const int* __restrict__ n_off,
                                                  const int* __restrict__ n_edges,
                                                  const __half* __restrict__ edge_feat_h,
                                                  float* __restrict__ out) {
    int wid = threadIdx.x >> 6, lane = threadIdx.x & 63;
    int g = lane >> 4, li = lane & 15;
    int row = blockIdx.x * 16 + wid * 4 + g;      // 6250*16 == 100000 exactly
    int beg = n_off[row], end = n_off[row + 1];
    int deg = end - beg;
    int dmax = deg;
    dmax = max(dmax, __shfl_xor(dmax, 16, 64));
    dmax = max(dmax, __shfl_xor(dmax, 32, 64));

    const uint4* ef4 = (const uint4*)edge_feat_h;
    float2 a0 = {0.f, 0.f}, a1 = {0.f, 0.f}, a2 = {0.f, 0.f}, a3 = {0.f, 0.f};
    #pragma unroll 2
    for (int t = 0; t < dmax; ++t) {
        if (t < deg) {
            int idx = n_edges[beg + t];
            uint4 q = ef4[(size_t)idx * 16 + li];
            float2 f0 = __half22float2(*(__half2*)&q.x);
            float2 f1 = __half22float2(*(__half2*)&q.y);
            float2 f2 = __half22float2(*(__half2*)&q.z);
            float2 f3 = __half22float2(*(__half2*)&q.w);
            a0.x += f0.x; a0.y += f0.y; a1.x += f1.x; a1.y += f1.y;
            a2.x += f2.x; a2.y += f2.y; a3.x += f3.x; a3.y += f3.y;
        }
    }
    float inv = 1.0f / fmaxf((float)deg, 1.0f);
    uint4 qp = ((const uint4*)probs_h)[(size_t)row * 16 + li];
    float2 p0 = __half22float2(*(__half2*)&qp.x);
    float2 p1 = __half22float2(*(__half2*)&qp.y);
    float2 p2 = __half22float2(*(__half2*)&qp.z);
    float2 p3 = __half22float2(*(__half2*)&qp.w);
    float v0 = fmaxf(p0.x, 1e-12f) * (a0.x * inv);
    float v1 = fmaxf(p0.y, 1e-12f) * (a0.y * inv);
    float v2 = fmaxf(p1.x, 1e-12f) * (a1.x * inv);
    float v3 = fmaxf(p1.y, 1e-12f) * (a1.y * inv);
    float v4 = fmaxf(p2.x, 1e-12f) * (a2.x * inv);
    float v5 = fmaxf(p2.y, 1e-12f) * (a2.y * inv);
    float v6 = fmaxf(p3.x, 1e-12f) * (a3.x * inv);
    float v7 = fmaxf(p3.y, 1e-12f) * (a3.y * inv);
    float s = ((v0 + v1) + (v2 + v3)) + ((v4 + v5) + (v6 + v7));
    #pragma unroll
    for (int off = 1; off <= 8; off <<= 1) s += __shfl_xor(s, off, 64);  // within 16-lane group
    float mean = s * (1.0f / (float)K);
    float* orow = out + (size_t)row * K + li * 8;
    *(float4*)orow       = make_float4(v0 - mean, v1 - mean, v2 - mean, v3 - mean);
    *(float4*)(orow + 4) = make_float4(v4 - mean, v5 - mean, v6 - mean, v7 - mean);
}

extern "C" void kernel_launch(void* const* d_in, const int* in_sizes, int n_in,
                              void* d_out, int out_size, void* d_ws, size_t ws_size,
                              hipStream_t stream) {
    const float* y        = (const float*)d_in[0];
    const float* W        = (const float*)d_in[1];
    const int*   node_idx = (const int*)d_in[2];
    const int*   edge_idx = (const int*)d_in[3];
    float* out = (float*)d_out;

    // workspace carve-up (4-byte units unless noted)
    unsigned* ebkt = (unsigned*)d_ws;                    // NNZ
    unsigned* nbkt = ebkt + NNZ;                         // NNZ
    int* e_nodes = (int*)(nbkt + NNZ);                   // NNZ
    int* n_edges = e_nodes + NNZ;                        // NNZ
    int* e_off   = n_edges + NNZ;                        // N_EDGES+1
    int* n_off   = e_off + (N_EDGES + 1);                // N_NODES+1
    int* ebcnt   = n_off + (N_NODES + 1);                // 200 (pad)
    int* nbcnt   = ebcnt + 200;                          // 200
    int* ebOff   = nbcnt + 200;                          // 200
    int* nbOff   = ebOff + 200;                          // 200
    int* ebCur   = nbOff + 200;                          // 200
    int* nbCur   = ebCur + 200;                          // 200
    uintptr_t pa = (uintptr_t)(nbCur + 200);
    pa = (pa + 255) & ~(uintptr_t)255;                   // 256B-align for dwordx4 row loads
    __half2* probs_h = (__half2*)pa;                     // N_NODES*64 half2 = 25.6 MB
    __half*  edge_feat_h = (__half*)ebkt;                // N_EDGES*K halves (6.4MB), aliases dead ebkt

    hipMemsetAsync(ebcnt, 0, 400 * sizeof(int), stream);

    bhist_k<<<1024, 256, 0, stream>>>(node_idx, edge_idx, ebcnt, nbcnt);
    bscan_k<<<1, 512, 0, stream>>>(ebcnt, nbcnt, ebOff, nbOff, ebCur, nbCur, e_off, n_off);
    bpart_k<<<(NNZ + 2047) / 2048, 256, 0, stream>>>(node_idx, edge_idx, ebCur, nbCur, ebkt, nbkt);
    bfill_k<<<NB_E + NB_N, 256, 0, stream>>>(ebkt, nbkt, ebOff, nbOff, e_off, n_off, e_nodes, n_edges);

    softmax_k<<<(N_NODES + 3) / 4, 256, 0, stream>>>(y, probs_h);
    mm2_k<<<(N_EDGES + 15) / 16, 256, 0, stream>>>(probs_h, e_off, e_nodes, W, edge_feat_h);
    node_fin_k<<<N_NODES / 16, 256, 0, stream>>>(probs_h, n_off, n_edges, edge_feat_h, out);
}

// Round 6
// 261.924 us; speedup vs baseline: 5.9579x; 1.0981x over previous
//
#include <hip/hip_runtime.h>
#include <hip/hip_fp16.h>

#define N_NODES 100000
#define N_EDGES 25000
#define K 128
#define NNZ 1600000

// edge buckets: 128 edges each; node buckets: 512 nodes each
#define NB_E 196   // ceil(25000/128)
#define NB_N 196   // ceil(100000/512)
// packed entry: (edge << 17) | node   (edge < 2^15, node < 2^17)

// -------- softmax over rows of y -> probs (fp16 out, f32 math) --------
__global__ __launch_bounds__(256) void softmax_k(const float* __restrict__ y,
                                                 __half2* __restrict__ probs_h) {
    int wid = threadIdx.x >> 6, lane = threadIdx.x & 63;
    int row = blockIdx.x * 4 + wid;
    if (row >= N_NODES) return;
    const float2* yr = (const float2*)(y + (size_t)row * K);
    float2 a = yr[lane];
    float m = fmaxf(a.x, a.y);
    #pragma unroll
    for (int off = 32; off >= 1; off >>= 1) m = fmaxf(m, __shfl_xor(m, off, 64));
    float e0 = expf(a.x - m);
    float e1 = expf(a.y - m);
    float s = e0 + e1;
    #pragma unroll
    for (int off = 32; off >= 1; off >>= 1) s += __shfl_xor(s, off, 64);
    float inv = 1.0f / s;
    probs_h[(size_t)row * 64 + lane] = __floats2half2_rn(e0 * inv, e1 * inv);
}

// ---------------- bucket histogram (both sides) ----------------
__global__ __launch_bounds__(256) void bhist_k(const int* __restrict__ ni,
                                               const int* __restrict__ ei,
                                               int* __restrict__ ebcnt,
                                               int* __restrict__ nbcnt) {
    __shared__ int se[NB_E], sn[NB_N];
    for (int t = threadIdx.x; t < NB_E; t += 256) se[t] = 0;
    for (int t = threadIdx.x; t < NB_N; t += 256) sn[t] = 0;
    __syncthreads();
    for (int i = blockIdx.x * 256 + threadIdx.x; i < NNZ; i += gridDim.x * 256) {
        atomicAdd(&se[ei[i] >> 7], 1);
        atomicAdd(&sn[ni[i] >> 9], 1);
    }
    __syncthreads();
    for (int t = threadIdx.x; t < NB_E; t += 256) if (se[t]) atomicAdd(&ebcnt[t], se[t]);
    for (int t = threadIdx.x; t < NB_N; t += 256) if (sn[t]) atomicAdd(&nbcnt[t], sn[t]);
}

// ---------------- scan bucket counts -> offsets + cursors ----------------
__global__ __launch_bounds__(512) void bscan_k(const int* __restrict__ ebcnt,
                                               const int* __restrict__ nbcnt,
                                               int* __restrict__ ebOff, int* __restrict__ nbOff,
                                               int* __restrict__ ebCur, int* __restrict__ nbCur,
                                               int* __restrict__ e_off, int* __restrict__ n_off) {
    __shared__ int s[512];
    int t = threadIdx.x;
    int half = t >> 8, idx = t & 255;
    int v = 0;
    if (half == 0) v = (idx < NB_E) ? ebcnt[idx] : 0;
    else           v = (idx < NB_N) ? nbcnt[idx] : 0;
    s[t] = v;
    __syncthreads();
    for (int d = 1; d < 256; d <<= 1) {
        int add = (idx >= d) ? s[t - d] : 0;
        __syncthreads();
        s[t] += add;
        __syncthreads();
    }
    int excl = s[t] - v;
    if (half == 0 && idx < NB_E) {
        ebOff[idx] = excl; ebCur[idx] = excl;
        if (idx == NB_E - 1) ebOff[NB_E] = excl + v;
    }
    if (half == 1 && idx < NB_N) {
        nbOff[idx] = excl; nbCur[idx] = excl;
        if (idx == NB_N - 1) nbOff[NB_N] = excl + v;
    }
    if (t == 0) { e_off[N_EDGES] = NNZ; n_off[N_NODES] = NNZ; }
}

// ---------------- partition entries into buckets (both sides) ----------------
__global__ __launch_bounds__(256) void bpart_k(const int* __restrict__ ni,
                                               const int* __restrict__ ei,
                                               int* __restrict__ ebCur, int* __restrict__ nbCur,
                                               unsigned* __restrict__ ebkt,
                                               unsigned* __restrict__ nbkt) {
    __shared__ int cnt[NB_E > NB_N ? NB_E : NB_N];
    __shared__ int runb[NB_E > NB_N ? NB_E : NB_N];
    unsigned pk[8]; int rk[8]; bool val[8];
    int i0 = blockIdx.x * 2048;
    #pragma unroll
    for (int k = 0; k < 8; ++k) {
        int i = i0 + threadIdx.x + k * 256;
        val[k] = (i < NNZ);
        pk[k] = val[k] ? (((unsigned)ei[i] << 17) | (unsigned)ni[i]) : 0u;
    }
    // ---- edge side: bucket = pk >> 24 ----
    for (int t = threadIdx.x; t < NB_E; t += 256) cnt[t] = 0;
    __syncthreads();
    #pragma unroll
    for (int k = 0; k < 8; ++k) if (val[k]) rk[k] = atomicAdd(&cnt[pk[k] >> 24], 1);
    __syncthreads();
    for (int t = threadIdx.x; t < NB_E; t += 256)
        runb[t] = cnt[t] ? atomicAdd(&ebCur[t], cnt[t]) : 0;
    __syncthreads();
    #pragma unroll
    for (int k = 0; k < 8; ++k) if (val[k]) ebkt[runb[pk[k] >> 24] + rk[k]] = pk[k];
    __syncthreads();
    // ---- node side: bucket = (pk >> 9) & 0xFF ----
    for (int t = threadIdx.x; t < NB_N; t += 256) cnt[t] = 0;
    __syncthreads();
    #pragma unroll
    for (int k = 0; k < 8; ++k) if (val[k]) rk[k] = atomicAdd(&cnt[(pk[k] >> 9) & 0xFF], 1);
    __syncthreads();
    for (int t = threadIdx.x; t < NB_N; t += 256)
        runb[t] = cnt[t] ? atomicAdd(&nbCur[t], cnt[t]) : 0;
    __syncthreads();
    #pragma unroll
    for (int k = 0; k < 8; ++k) if (val[k]) nbkt[runb[(pk[k] >> 9) & 0xFF] + rk[k]] = pk[k];
}

// ------- per-bucket: counts -> local scan -> csr offsets + ranked fill -------
__global__ __launch_bounds__(256) void bfill_k(const unsigned* __restrict__ ebkt,
                                               const unsigned* __restrict__ nbkt,
                                               const int* __restrict__ ebOff,
                                               const int* __restrict__ nbOff,
                                               int* __restrict__ e_off, int* __restrict__ n_off,
                                               int* __restrict__ e_nodes,
                                               int* __restrict__ n_edges) {
    __shared__ int cnt[512];
    __shared__ int par[256];
    int b = blockIdx.x;
    int t = threadIdx.x;
    if (b < NB_E) {
        int beg = ebOff[b], end = ebOff[b + 1];
        for (int x = t; x < 128; x += 256) cnt[x] = 0;
        __syncthreads();
        int i = beg + t;
        for (; i + 768 < end; i += 1024) {
            unsigned p0 = ebkt[i], p1 = ebkt[i + 256], p2 = ebkt[i + 512], p3 = ebkt[i + 768];
            atomicAdd(&cnt[(p0 >> 17) & 127], 1);
            atomicAdd(&cnt[(p1 >> 17) & 127], 1);
            atomicAdd(&cnt[(p2 >> 17) & 127], 1);
            atomicAdd(&cnt[(p3 >> 17) & 127], 1);
        }
        for (; i < end; i += 256) atomicAdd(&cnt[(ebkt[i] >> 17) & 127], 1);
        __syncthreads();
        int v = (t < 128) ? cnt[t] : 0;
        par[t] = v;
        __syncthreads();
        for (int d = 1; d < 256; d <<= 1) {
            int add = (t >= d) ? par[t - d] : 0;
            __syncthreads();
            par[t] += add;
            __syncthreads();
        }
        if (t < 128) {
            int excl = par[t] - v;
            cnt[t] = excl;
            int e = (b << 7) + t;
            if (e < N_EDGES) e_off[e] = beg + excl;
        }
        __syncthreads();
        i = beg + t;
        for (; i + 768 < end; i += 1024) {
            unsigned p0 = ebkt[i], p1 = ebkt[i + 256], p2 = ebkt[i + 512], p3 = ebkt[i + 768];
            int d0 = atomicAdd(&cnt[(p0 >> 17) & 127], 1);
            int d1 = atomicAdd(&cnt[(p1 >> 17) & 127], 1);
            int d2 = atomicAdd(&cnt[(p2 >> 17) & 127], 1);
            int d3 = atomicAdd(&cnt[(p3 >> 17) & 127], 1);
            e_nodes[beg + d0] = p0 & 0x1FFFF;
            e_nodes[beg + d1] = p1 & 0x1FFFF;
            e_nodes[beg + d2] = p2 & 0x1FFFF;
            e_nodes[beg + d3] = p3 & 0x1FFFF;
        }
        for (; i < end; i += 256) {
            unsigned p = ebkt[i];
            int d = atomicAdd(&cnt[(p >> 17) & 127], 1);
            e_nodes[beg + d] = p & 0x1FFFF;
        }
    } else {
        int b2 = b - NB_E;
        int beg = nbOff[b2], end = nbOff[b2 + 1];
        for (int x = t; x < 512; x += 256) cnt[x] = 0;
        __syncthreads();
        int i = beg + t;
        for (; i + 768 < end; i += 1024) {
            unsigned p0 = nbkt[i], p1 = nbkt[i + 256], p2 = nbkt[i + 512], p3 = nbkt[i + 768];
            atomicAdd(&cnt[p0 & 511], 1);
            atomicAdd(&cnt[p1 & 511], 1);
            atomicAdd(&cnt[p2 & 511], 1);
            atomicAdd(&cnt[p3 & 511], 1);
        }
        for (; i < end; i += 256) atomicAdd(&cnt[nbkt[i] & 511], 1);
        __syncthreads();
        int v0 = cnt[t * 2], v1 = cnt[t * 2 + 1];
        int vs = v0 + v1;
        par[t] = vs;
        __syncthreads();
        for (int d = 1; d < 256; d <<= 1) {
            int add = (t >= d) ? par[t - d] : 0;
            __syncthreads();
            par[t] += add;
            __syncthreads();
        }
        int excl = par[t] - vs;
        __syncthreads();
        cnt[t * 2] = excl;
        cnt[t * 2 + 1] = excl + v0;
        int n = (b2 << 9) + t * 2;
        if (n < N_NODES)     n_off[n]     = beg + excl;
        if (n + 1 < N_NODES) n_off[n + 1] = beg + excl + v0;
        __syncthreads();
        i = beg + t;
        for (; i + 768 < end; i += 1024) {
            unsigned p0 = nbkt[i], p1 = nbkt[i + 256], p2 = nbkt[i + 512], p3 = nbkt[i + 768];
            int d0 = atomicAdd(&cnt[p0 & 511], 1);
            int d1 = atomicAdd(&cnt[p1 & 511], 1);
            int d2 = atomicAdd(&cnt[p2 & 511], 1);
            int d3 = atomicAdd(&cnt[p3 & 511], 1);
            n_edges[beg + d0] = p0 >> 17;
            n_edges[beg + d1] = p1 >> 17;
            n_edges[beg + d2] = p2 >> 17;
            n_edges[beg + d3] = p3 >> 17;
        }
        for (; i < end; i += 256) {
            unsigned p = nbkt[i];
            int d = atomicAdd(&cnt[p & 511], 1);
            n_edges[beg + d] = p >> 17;
        }
    }
}

// ------- fused: gather probs(fp16, 16 lanes/row, 4-deep MLP) -> edge mean -> @W -> edge_feat(fp16) -------
// 256 threads = 4 waves; block owns 16 edges; wave w owns edges w*4..w*4+3.
// Gather: lane-group g=lane>>4 handles entries beg+g, beg+4+g, ... (stride 4);
// main loop runs 4 entries (16B each lane) per iteration, branch-free.
__global__ __launch_bounds__(256) void mm2_k(const __half2* __restrict__ probs_h,
                                             const int* __restrict__ e_off,
                                             const int* __restrict__ e_nodes,
                                             const float* __restrict__ W,
                                             __half* __restrict__ edge_feat_h) {
    __shared__ float a_s[16][K];
    int wid = threadIdx.x >> 6, lane = threadIdx.x & 63;
    int g = lane >> 4, li = lane & 15;
    const uint4* pr4 = (const uint4*)probs_h;      // 16 uint4 per 256B row

    for (int rr = 0; rr < 4; ++rr) {
        int e = blockIdx.x * 16 + wid * 4 + rr;
        int beg = 0, end = 0;
        if (e < N_EDGES) { beg = e_off[e]; end = e_off[e + 1]; }
        float2 a0 = {0.f, 0.f}, a1 = {0.f, 0.f}, a2 = {0.f, 0.f}, a3 = {0.f, 0.f};
        int j = beg + g;
        // main loop: 4 independent idx->row chains in flight per group
        for (; j + 12 < end; j += 16) {
            int i0 = e_nodes[j];
            int i1 = e_nodes[j + 4];
            int i2 = e_nodes[j + 8];
            int i3 = e_nodes[j + 12];
            uint4 q0 = pr4[(size_t)i0 * 16 + li];
            uint4 q1 = pr4[(size_t)i1 * 16 + li];
            uint4 q2 = pr4[(size_t)i2 * 16 + li];
            uint4 q3 = pr4[(size_t)i3 * 16 + li];
            float2 f;
            f = __half22float2(*(__half2*)&q0.x); a0.x += f.x; a0.y += f.y;
            f = __half22float2(*(__half2*)&q0.y); a1.x += f.x; a1.y += f.y;
            f = __half22float2(*(__half2*)&q0.z); a2.x += f.x; a2.y += f.y;
            f = __half22float2(*(__half2*)&q0.w); a3.x += f.x; a3.y += f.y;
            f = __half22float2(*(__half2*)&q1.x); a0.x += f.x; a0.y += f.y;
            f = __half22float2(*(__half2*)&q1.y); a1.x += f.x; a1.y += f.y;
            f = __half22float2(*(__half2*)&q1.z); a2.x += f.x; a2.y += f.y;
            f = __half22float2(*(__half2*)&q1.w); a3.x += f.x; a3.y += f.y;
            f = __half22float2(*(__half2*)&q2.x); a0.x += f.x; a0.y += f.y;
            f = __half22float2(*(__half2*)&q2.y); a1.x += f.x; a1.y += f.y;
            f = __half22float2(*(__half2*)&q2.z); a2.x += f.x; a2.y += f.y;
            f = __half22float2(*(__half2*)&q2.w); a3.x += f.x; a3.y += f.y;
            f = __half22float2(*(__half2*)&q3.x); a0.x += f.x; a0.y += f.y;
            f = __half22float2(*(__half2*)&q3.y); a1.x += f.x; a1.y += f.y;
            f = __half22float2(*(__half2*)&q3.z); a2.x += f.x; a2.y += f.y;
            f = __half22float2(*(__half2*)&q3.w); a3.x += f.x; a3.y += f.y;
        }
        for (; j < end; j += 4) {
            int idx = e_nodes[j];
            uint4 q = pr4[(size_t)idx * 16 + li];
            float2 f;
            f = __half22float2(*(__half2*)&q.x); a0.x += f.x; a0.y += f.y;
            f = __half22float2(*(__half2*)&q.y); a1.x += f.x; a1.y += f.y;
            f = __half22float2(*(__half2*)&q.z); a2.x += f.x; a2.y += f.y;
            f = __half22float2(*(__half2*)&q.w); a3.x += f.x; a3.y += f.y;
        }
        // combine the 4 lane-groups
        #pragma unroll
        for (int off = 16; off <= 32; off <<= 1) {
            a0.x += __shfl_xor(a0.x, off, 64); a0.y += __shfl_xor(a0.y, off, 64);
            a1.x += __shfl_xor(a1.x, off, 64); a1.y += __shfl_xor(a1.y, off, 64);
            a2.x += __shfl_xor(a2.x, off, 64); a2.y += __shfl_xor(a2.y, off, 64);
            a3.x += __shfl_xor(a3.x, off, 64); a3.y += __shfl_xor(a3.y, off, 64);
        }
        float inv = 1.0f / fmaxf((float)(end - beg), 1.0f);
        if (g == 0) {
            float* as = &a_s[wid * 4 + rr][li * 8];
            *(float4*)as       = make_float4(a0.x * inv, a0.y * inv, a1.x * inv, a1.y * inv);
            *(float4*)(as + 4) = make_float4(a2.x * inv, a2.y * inv, a3.x * inv, a3.y * inv);
        }
    }
    __syncthreads();

    // GEMM: thread (rq = tid>>6, jp = tid&63) computes rows rq*4..+3, cols jp*2,jp*2+1
    int rq = threadIdx.x >> 6;
    int jp = threadIdx.x & 63;
    float2 c0 = {0.f, 0.f}, c1 = {0.f, 0.f}, c2 = {0.f, 0.f}, c3 = {0.f, 0.f};
    for (int k = 0; k < K; k += 4) {
        float4 b0 = *(float4*)&a_s[rq * 4 + 0][k];
        float4 b1 = *(float4*)&a_s[rq * 4 + 1][k];
        float4 b2 = *(float4*)&a_s[rq * 4 + 2][k];
        float4 b3 = *(float4*)&a_s[rq * 4 + 3][k];
        float2 w0 = *(const float2*)&W[(k + 0) * K + jp * 2];
        float2 w1 = *(const float2*)&W[(k + 1) * K + jp * 2];
        float2 w2 = *(const float2*)&W[(k + 2) * K + jp * 2];
        float2 w3 = *(const float2*)&W[(k + 3) * K + jp * 2];
        c0.x += b0.x * w0.x + b0.y * w1.x + b0.z * w2.x + b0.w * w3.x;
        c0.y += b0.x * w0.y + b0.y * w1.y + b0.z * w2.y + b0.w * w3.y;
        c1.x += b1.x * w0.x + b1.y * w1.x + b1.z * w2.x + b1.w * w3.x;
        c1.y += b1.x * w0.y + b1.y * w1.y + b1.z * w2.y + b1.w * w3.y;
        c2.x += b2.x * w0.x + b2.y * w1.x + b2.z * w2.x + b2.w * w3.x;
        c2.y += b2.x * w0.y + b2.y * w1.y + b2.z * w2.y + b2.w * w3.y;
        c3.x += b3.x * w0.x + b3.y * w1.x + b3.z * w2.x + b3.w * w3.x;
        c3.y += b3.x * w0.y + b3.y * w1.y + b3.z * w2.y + b3.w * w3.y;
    }
    __half2* ef2 = (__half2*)edge_feat_h;
    int r0 = blockIdx.x * 16 + rq * 4;
    if (r0 + 0 < N_EDGES) ef2[(size_t)(r0 + 0) * 64 + jp] = __floats2half2_rn(c0.x, c0.y);
    if (r0 + 1 < N_EDGES) ef2[(size_t)(r0 + 1) * 64 + jp] = __floats2half2_rn(c1.x, c1.y);
    if (r0 + 2 < N_EDGES) ef2[(size_t)(r0 + 2) * 64 + jp] = __floats2half2_rn(c2.x, c2.y);
    if (r0 + 3 < N_EDGES) ef2[(size_t)(r0 + 3) * 64 + jp] = __floats2half2_rn(c3.x, c3.y);
}

// ------- fused: gather edge_feat(fp16, 4-deep MLP) -> node mean; nat-grad; mean-center -------
// 256 threads = 4 waves; block owns 16 nodes; wave owns 4 (lane-group g per node).
__global__ __launch_bounds__(256) void node_fin_k(const __half2* __restrict__ probs_h,
                                                  const int* __restrict__ n_off,
                                                  const int* __restrict__ n_edges,
                                                  const __half* __restrict__ edge_feat_h,
                                                  float* __restrict__ out) {
    int wid = threadIdx.x >> 6, lane = threadIdx.x & 63;
    int g = lane >> 4, li = lane & 15;
    int row = blockIdx.x * 16 + wid * 4 + g;      // 6250*16 == 100000 exactly
    int beg = n_off[row], end = n_off[row + 1];
    int deg = end - beg;

    const uint4* ef4 = (const uint4*)edge_feat_h;
    float2 a0 = {0.f, 0.f}, a1 = {0.f, 0.f}, a2 = {0.f, 0.f}, a3 = {0.f, 0.f};
    int t = beg;
    for (; t + 3 < end; t += 4) {
        int i0 = n_edges[t];
        int i1 = n_edges[t + 1];
        int i2 = n_edges[t + 2];
        int i3 = n_edges[t + 3];
        uint4 q0 = ef4[(size_t)i0 * 16 + li];
        uint4 q1 = ef4[(size_t)i1 * 16 + li];
        uint4 q2 = ef4[(size_t)i2 * 16 + li];
        uint4 q3 = ef4[(size_t)i3 * 16 + li];
        float2 f;
        f = __half22float2(*(__half2*)&q0.x); a0.x += f.x; a0.y += f.y;
        f = __half22float2(*(__half2*)&q0.y); a1.x += f.x; a1.y += f.y;
        f = __half22float2(*(__half2*)&q0.z); a2.x += f.x; a2.y += f.y;
        f = __half22float2(*(__half2*)&q0.w); a3.x += f.x; a3.y += f.y;
        f = __half22float2(*(__half2*)&q1.x); a0.x += f.x; a0.y += f.y;
        f = __half22float2(*(__half2*)&q1.y); a1.x += f.x; a1.y += f.y;
        f = __half22float2(*(__half2*)&q1.z); a2.x += f.x; a2.y += f.y;
        f = __half22float2(*(__half2*)&q1.w); a3.x += f.x; a3.y += f.y;
        f = __half22float2(*(__half2*)&q2.x); a0.x += f.x; a0.y += f.y;
        f = __half22float2(*(__half2*)&q2.y); a1.x += f.x; a1.y += f.y;
        f = __half22float2(*(__half2*)&q2.z); a2.x += f.x; a2.y += f.y;
        f = __half22float2(*(__half2*)&q2.w); a3.x += f.x; a3.y += f.y;
        f = __half22float2(*(__half2*)&q3.x); a0.x += f.x; a0.y += f.y;
        f = __half22float2(*(__half2*)&q3.y); a1.x += f.x; a1.y += f.y;
        f = __half22float2(*(__half2*)&q3.z); a2.x += f.x; a2.y += f.y;
        f = __half22float2(*(__half2*)&q3.w); a3.x += f.x; a3.y += f.y;
    }
    for (; t < end; ++t) {
        int idx = n_edges[t];
        uint4 q = ef4[(size_t)idx * 16 + li];
        float2 f;
        f = __half22float2(*(__half2*)&q.x); a0.x += f.x; a0.y += f.y;
        f = __half22float2(*(__half2*)&q.y); a1.x += f.x; a1.y += f.y;
        f = __half22float2(*(__half2*)&q.z); a2.x += f.x; a2.y += f.y;
        f = __half22float2(*(__half2*)&q.w); a3.x += f.x; a3.y += f.y;
    }
    float inv = 1.0f / fmaxf((float)deg, 1.0f);
    uint4 qp = ((const uint4*)probs_h)[(size_t)row * 16 + li];
    float2 p0 = __half22float2(*(__half2*)&qp.x);
    float2 p1 = __half22float2(*(__half2*)&qp.y);
    float2 p2 = __half22float2(*(__half2*)&qp.z);
    float2 p3 = __half22float2(*(__half2*)&qp.w);
    float v0 = fmaxf(p0.x, 1e-12f) * (a0.x * inv);
    float v1 = fmaxf(p0.y, 1e-12f) * (a0.y * inv);
    float v2 = fmaxf(p1.x, 1e-12f) * (a1.x * inv);
    float v3 = fmaxf(p1.y, 1e-12f) * (a1.y * inv);
    float v4 = fmaxf(p2.x, 1e-12f) * (a2.x * inv);
    float v5 = fmaxf(p2.y, 1e-12f) * (a2.y * inv);
    float v6 = fmaxf(p3.x, 1e-12f) * (a3.x * inv);
    float v7 = fmaxf(p3.y, 1e-12f) * (a3.y * inv);
    float s = ((v0 + v1) + (v2 + v3)) + ((v4 + v5) + (v6 + v7));
    #pragma unroll
    for (int off = 1; off <= 8; off <<= 1) s += __shfl_xor(s, off, 64);  // within 16-lane group
    float mean = s * (1.0f / (float)K);
    float* orow = out + (size_t)row * K + li * 8;
    *(float4*)orow       = make_float4(v0 - mean, v1 - mean, v2 - mean, v3 - mean);
    *(float4*)(orow + 4) = make_float4(v4 - mean, v5 - mean, v6 - mean, v7 - mean);
}

extern "C" void kernel_launch(void* const* d_in, const int* in_sizes, int n_in,
                              void* d_out, int out_size, void* d_ws, size_t ws_size,
                              hipStream_t stream) {
    const float* y        = (const float*)d_in[0];
    const float* W        = (const float*)d_in[1];
    const int*   node_idx = (const int*)d_in[2];
    const int*   edge_idx = (const int*)d_in[3];
    float* out = (float*)d_out;

    // workspace carve-up (4-byte units unless noted)
    unsigned* ebkt = (unsigned*)d_ws;                    // NNZ
    unsigned* nbkt = ebkt + NNZ;                         // NNZ
    int* e_nodes = (int*)(nbkt + NNZ);                   // NNZ
    int* n_edges = e_nodes + NNZ;                        // NNZ
    int* e_off   = n_edges + NNZ;                        // N_EDGES+1
    int* n_off   = e_off + (N_EDGES + 1);                // N_NODES+1
    int* ebcnt   = n_off + (N_NODES + 1);                // 200 (pad)
    int* nbcnt   = ebcnt + 200;                          // 200
    int* ebOff   = nbcnt + 200;                          // 200
    int* nbOff   = ebOff + 200;                          // 200
    int* ebCur   = nbOff + 200;                          // 200
    int* nbCur   = ebCur + 200;                          // 200
    uintptr_t pa = (uintptr_t)(nbCur + 200);
    pa = (pa + 255) & ~(uintptr_t)255;                   // 256B-align for dwordx4 row loads
    __half2* probs_h = (__half2*)pa;                     // N_NODES*64 half2 = 25.6 MB
    __half*  edge_feat_h = (__half*)ebkt;                // N_EDGES*K halves (6.4MB), aliases dead ebkt

    hipMemsetAsync(ebcnt, 0, 400 * sizeof(int), stream);

    bhist_k<<<1024, 256, 0, stream>>>(node_idx, edge_idx, ebcnt, nbcnt);
    bscan_k<<<1, 512, 0, stream>>>(ebcnt, nbcnt, ebOff, nbOff, ebCur, nbCur, e_off, n_off);
    bpart_k<<<(NNZ + 2047) / 2048, 256, 0, stream>>>(node_idx, edge_idx, ebCur, nbCur, ebkt, nbkt);
    bfill_k<<<NB_E + NB_N, 256, 0, stream>>>(ebkt, nbkt, ebOff, nbOff, e_off, n_off, e_nodes, n_edges);

    softmax_k<<<(N_NODES + 3) / 4, 256, 0, stream>>>(y, probs_h);
    mm2_k<<<(N_EDGES + 15) / 16, 256, 0, stream>>>(probs_h, e_off, e_nodes, W, edge_feat_h);
    node_fin_k<<<N_NODES / 16, 256, 0, stream>>>(probs_h, n_off, n_edges, edge_feat_h, out);
}

// Round 7
// 238.418 us; speedup vs baseline: 6.5453x; 1.0986x over previous
//
#include <hip/hip_runtime.h>
#include <hip/hip_fp16.h>

#define N_NODES 100000
#define N_EDGES 25000
#define K 128
#define NNZ 1600000

// edge buckets: 128 edges each; node buckets: 512 nodes each
#define NB_E 196   // ceil(25000/128)
#define NB_N 196   // ceil(100000/512)
// packed entry: (edge << 17) | node   (edge < 2^15, node < 2^17)

typedef float v2f __attribute__((ext_vector_type(2)));

// -------- softmax over rows of y -> probs (fp16 + fp8 out, f32 math) --------
__global__ __launch_bounds__(256) void softmax_k(const float* __restrict__ y,
                                                 __half2* __restrict__ probs_h,
                                                 unsigned short* __restrict__ probs8) {
    int wid = threadIdx.x >> 6, lane = threadIdx.x & 63;
    int row = blockIdx.x * 4 + wid;
    if (row >= N_NODES) return;
    const float2* yr = (const float2*)(y + (size_t)row * K);
    float2 a = yr[lane];
    float m = fmaxf(a.x, a.y);
    #pragma unroll
    for (int off = 32; off >= 1; off >>= 1) m = fmaxf(m, __shfl_xor(m, off, 64));
    float e0 = expf(a.x - m);
    float e1 = expf(a.y - m);
    float s = e0 + e1;
    #pragma unroll
    for (int off = 32; off >= 1; off >>= 1) s += __shfl_xor(s, off, 64);
    float inv = 1.0f / s;
    float p0 = e0 * inv, p1 = e1 * inv;
    probs_h[(size_t)row * 64 + lane] = __floats2half2_rn(p0, p1);
    int pk = __builtin_amdgcn_cvt_pk_fp8_f32(p0, p1, 0, false);   // e4m3 (OCP on gfx950)
    probs8[(size_t)row * 64 + lane] = (unsigned short)(pk & 0xFFFF);
}

// ---------------- bucket histogram (both sides) ----------------
__global__ __launch_bounds__(256) void bhist_k(const int* __restrict__ ni,
                                               const int* __restrict__ ei,
                                               int* __restrict__ ebcnt,
                                               int* __restrict__ nbcnt) {
    __shared__ int se[NB_E], sn[NB_N];
    for (int t = threadIdx.x; t < NB_E; t += 256) se[t] = 0;
    for (int t = threadIdx.x; t < NB_N; t += 256) sn[t] = 0;
    __syncthreads();
    for (int i = blockIdx.x * 256 + threadIdx.x; i < NNZ; i += gridDim.x * 256) {
        atomicAdd(&se[ei[i] >> 7], 1);
        atomicAdd(&sn[ni[i] >> 9], 1);
    }
    __syncthreads();
    for (int t = threadIdx.x; t < NB_E; t += 256) if (se[t]) atomicAdd(&ebcnt[t], se[t]);
    for (int t = threadIdx.x; t < NB_N; t += 256) if (sn[t]) atomicAdd(&nbcnt[t], sn[t]);
}

// ---------------- scan bucket counts -> offsets + cursors ----------------
__global__ __launch_bounds__(512) void bscan_k(const int* __restrict__ ebcnt,
                                               const int* __restrict__ nbcnt,
                                               int* __restrict__ ebOff, int* __restrict__ nbOff,
                                               int* __restrict__ ebCur, int* __restrict__ nbCur,
                                               int* __restrict__ e_off, int* __restrict__ n_off) {
    __shared__ int s[512];
    int t = threadIdx.x;
    int half = t >> 8, idx = t & 255;
    int v = 0;
    if (half == 0) v = (idx < NB_E) ? ebcnt[idx] : 0;
    else           v = (idx < NB_N) ? nbcnt[idx] : 0;
    s[t] = v;
    __syncthreads();
    for (int d = 1; d < 256; d <<= 1) {
        int add = (idx >= d) ? s[t - d] : 0;
        __syncthreads();
        s[t] += add;
        __syncthreads();
    }
    int excl = s[t] - v;
    if (half == 0 && idx < NB_E) {
        ebOff[idx] = excl; ebCur[idx] = excl;
        if (idx == NB_E - 1) ebOff[NB_E] = excl + v;
    }
    if (half == 1 && idx < NB_N) {
        nbOff[idx] = excl; nbCur[idx] = excl;
        if (idx == NB_N - 1) nbOff[NB_N] = excl + v;
    }
    if (t == 0) { e_off[N_EDGES] = NNZ; n_off[N_NODES] = NNZ; }
}

// ---------------- partition entries into buckets (both sides) ----------------
__global__ __launch_bounds__(256) void bpart_k(const int* __restrict__ ni,
                                               const int* __restrict__ ei,
                                               int* __restrict__ ebCur, int* __restrict__ nbCur,
                                               unsigned* __restrict__ ebkt,
                                               unsigned* __restrict__ nbkt) {
    __shared__ int cnt[NB_E > NB_N ? NB_E : NB_N];
    __shared__ int runb[NB_E > NB_N ? NB_E : NB_N];
    unsigned pk[8]; int rk[8]; bool val[8];
    int i0 = blockIdx.x * 2048;
    #pragma unroll
    for (int k = 0; k < 8; ++k) {
        int i = i0 + threadIdx.x + k * 256;
        val[k] = (i < NNZ);
        pk[k] = val[k] ? (((unsigned)ei[i] << 17) | (unsigned)ni[i]) : 0u;
    }
    // ---- edge side: bucket = pk >> 24 ----
    for (int t = threadIdx.x; t < NB_E; t += 256) cnt[t] = 0;
    __syncthreads();
    #pragma unroll
    for (int k = 0; k < 8; ++k) if (val[k]) rk[k] = atomicAdd(&cnt[pk[k] >> 24], 1);
    __syncthreads();
    for (int t = threadIdx.x; t < NB_E; t += 256)
        runb[t] = cnt[t] ? atomicAdd(&ebCur[t], cnt[t]) : 0;
    __syncthreads();
    #pragma unroll
    for (int k = 0; k < 8; ++k) if (val[k]) ebkt[runb[pk[k] >> 24] + rk[k]] = pk[k];
    __syncthreads();
    // ---- node side: bucket = (pk >> 9) & 0xFF ----
    for (int t = threadIdx.x; t < NB_N; t += 256) cnt[t] = 0;
    __syncthreads();
    #pragma unroll
    for (int k = 0; k < 8; ++k) if (val[k]) rk[k] = atomicAdd(&cnt[(pk[k] >> 9) & 0xFF], 1);
    __syncthreads();
    for (int t = threadIdx.x; t < NB_N; t += 256)
        runb[t] = cnt[t] ? atomicAdd(&nbCur[t], cnt[t]) : 0;
    __syncthreads();
    #pragma unroll
    for (int k = 0; k < 8; ++k) if (val[k]) nbkt[runb[(pk[k] >> 9) & 0xFF] + rk[k]] = pk[k];
}

// ------- per-bucket: counts -> local scan -> csr offsets + ranked fill -------
__global__ __launch_bounds__(256) void bfill_k(const unsigned* __restrict__ ebkt,
                                               const unsigned* __restrict__ nbkt,
                                               const int* __restrict__ ebOff,
                                               const int* __restrict__ nbOff,
                                               int* __restrict__ e_off, int* __restrict__ n_off,
                                               int* __restrict__ e_nodes,
                                               int* __restrict__ n_edges) {
    __shared__ int cnt[512];
    __shared__ int par[256];
    int b = blockIdx.x;
    int t = threadIdx.x;
    if (b < NB_E) {
        int beg = ebOff[b], end = ebOff[b + 1];
        for (int x = t; x < 128; x += 256) cnt[x] = 0;
        __syncthreads();
        int i = beg + t;
        for (; i + 768 < end; i += 1024) {
            unsigned p0 = ebkt[i], p1 = ebkt[i + 256], p2 = ebkt[i + 512], p3 = ebkt[i + 768];
            atomicAdd(&cnt[(p0 >> 17) & 127], 1);
            atomicAdd(&cnt[(p1 >> 17) & 127], 1);
            atomicAdd(&cnt[(p2 >> 17) & 127], 1);
            atomicAdd(&cnt[(p3 >> 17) & 127], 1);
        }
        for (; i < end; i += 256) atomicAdd(&cnt[(ebkt[i] >> 17) & 127], 1);
        __syncthreads();
        int v = (t < 128) ? cnt[t] : 0;
        par[t] = v;
        __syncthreads();
        for (int d = 1; d < 256; d <<= 1) {
            int add = (t >= d) ? par[t - d] : 0;
            __syncthreads();
            par[t] += add;
            __syncthreads();
        }
        if (t < 128) {
            int excl = par[t] - v;
            cnt[t] = excl;
            int e = (b << 7) + t;
            if (e < N_EDGES) e_off[e] = beg + excl;
        }
        __syncthreads();
        i = beg + t;
        for (; i + 768 < end; i += 1024) {
            unsigned p0 = ebkt[i], p1 = ebkt[i + 256], p2 = ebkt[i + 512], p3 = ebkt[i + 768];
            int d0 = atomicAdd(&cnt[(p0 >> 17) & 127], 1);
            int d1 = atomicAdd(&cnt[(p1 >> 17) & 127], 1);
            int d2 = atomicAdd(&cnt[(p2 >> 17) & 127], 1);
            int d3 = atomicAdd(&cnt[(p3 >> 17) & 127], 1);
            e_nodes[beg + d0] = p0 & 0x1FFFF;
            e_nodes[beg + d1] = p1 & 0x1FFFF;
            e_nodes[beg + d2] = p2 & 0x1FFFF;
            e_nodes[beg + d3] = p3 & 0x1FFFF;
        }
        for (; i < end; i += 256) {
            unsigned p = ebkt[i];
            int d = atomicAdd(&cnt[(p >> 17) & 127], 1);
            e_nodes[beg + d] = p & 0x1FFFF;
        }
    } else {
        int b2 = b - NB_E;
        int beg = nbOff[b2], end = nbOff[b2 + 1];
        for (int x = t; x < 512; x += 256) cnt[x] = 0;
        __syncthreads();
        int i = beg + t;
        for (; i + 768 < end; i += 1024) {
            unsigned p0 = nbkt[i], p1 = nbkt[i + 256], p2 = nbkt[i + 512], p3 = nbkt[i + 768];
            atomicAdd(&cnt[p0 & 511], 1);
            atomicAdd(&cnt[p1 & 511], 1);
            atomicAdd(&cnt[p2 & 511], 1);
            atomicAdd(&cnt[p3 & 511], 1);
        }
        for (; i < end; i += 256) atomicAdd(&cnt[nbkt[i] & 511], 1);
        __syncthreads();
        int v0 = cnt[t * 2], v1 = cnt[t * 2 + 1];
        int vs = v0 + v1;
        par[t] = vs;
        __syncthreads();
        for (int d = 1; d < 256; d <<= 1) {
            int add = (t >= d) ? par[t - d] : 0;
            __syncthreads();
            par[t] += add;
            __syncthreads();
        }
        int excl = par[t] - vs;
        __syncthreads();
        cnt[t * 2] = excl;
        cnt[t * 2 + 1] = excl + v0;
        int n = (b2 << 9) + t * 2;
        if (n < N_NODES)     n_off[n]     = beg + excl;
        if (n + 1 < N_NODES) n_off[n + 1] = beg + excl + v0;
        __syncthreads();
        i = beg + t;
        for (; i + 768 < end; i += 1024) {
            unsigned p0 = nbkt[i], p1 = nbkt[i + 256], p2 = nbkt[i + 512], p3 = nbkt[i + 768];
            int d0 = atomicAdd(&cnt[p0 & 511], 1);
            int d1 = atomicAdd(&cnt[p1 & 511], 1);
            int d2 = atomicAdd(&cnt[p2 & 511], 1);
            int d3 = atomicAdd(&cnt[p3 & 511], 1);
            n_edges[beg + d0] = p0 >> 17;
            n_edges[beg + d1] = p1 >> 17;
            n_edges[beg + d2] = p2 >> 17;
            n_edges[beg + d3] = p3 >> 17;
        }
        for (; i < end; i += 256) {
            unsigned p = nbkt[i];
            int d = atomicAdd(&cnt[p & 511], 1);
            n_edges[beg + d] = p >> 17;
        }
    }
}

// ------- fused: gather probs(fp8, 16 lanes/row, 4-deep MLP) -> edge mean -> @W -> edge_feat(fp16) -------
// 256 threads = 4 waves; block owns 16 edges; wave w owns edges w*4..w*4+3.
// fp8 row = 128 B; lane li loads 8 B (8 fp8 = cols li*8..+7); HW cvt_pk_f32_fp8 decode.
__global__ __launch_bounds__(256) void mm2_k(const unsigned* __restrict__ probs8,
                                             const int* __restrict__ e_off,
                                             const int* __restrict__ e_nodes,
                                             const float* __restrict__ W,
                                             __half* __restrict__ edge_feat_h) {
    __shared__ float a_s[16][K];
    int wid = threadIdx.x >> 6, lane = threadIdx.x & 63;
    int g = lane >> 4, li = lane & 15;
    const uint2* pr2 = (const uint2*)probs8;      // 16 uint2 per 128B row

    for (int rr = 0; rr < 4; ++rr) {
        int e = blockIdx.x * 16 + wid * 4 + rr;
        int beg = 0, end = 0;
        if (e < N_EDGES) { beg = e_off[e]; end = e_off[e + 1]; }
        float2 a0 = {0.f, 0.f}, a1 = {0.f, 0.f}, a2 = {0.f, 0.f}, a3 = {0.f, 0.f};
        int j = beg + g;
        // main loop: 4 independent idx->row chains in flight per group
        for (; j + 12 < end; j += 16) {
            int i0 = e_nodes[j];
            int i1 = e_nodes[j + 4];
            int i2 = e_nodes[j + 8];
            int i3 = e_nodes[j + 12];
            uint2 q0 = pr2[(size_t)i0 * 16 + li];
            uint2 q1 = pr2[(size_t)i1 * 16 + li];
            uint2 q2 = pr2[(size_t)i2 * 16 + li];
            uint2 q3 = pr2[(size_t)i3 * 16 + li];
            v2f f;
            f = __builtin_amdgcn_cvt_pk_f32_fp8((int)q0.x, false); a0.x += f.x; a0.y += f.y;
            f = __builtin_amdgcn_cvt_pk_f32_fp8((int)q0.x, true);  a1.x += f.x; a1.y += f.y;
            f = __builtin_amdgcn_cvt_pk_f32_fp8((int)q0.y, false); a2.x += f.x; a2.y += f.y;
            f = __builtin_amdgcn_cvt_pk_f32_fp8((int)q0.y, true);  a3.x += f.x; a3.y += f.y;
            f = __builtin_amdgcn_cvt_pk_f32_fp8((int)q1.x, false); a0.x += f.x; a0.y += f.y;
            f = __builtin_amdgcn_cvt_pk_f32_fp8((int)q1.x, true);  a1.x += f.x; a1.y += f.y;
            f = __builtin_amdgcn_cvt_pk_f32_fp8((int)q1.y, false); a2.x += f.x; a2.y += f.y;
            f = __builtin_amdgcn_cvt_pk_f32_fp8((int)q1.y, true);  a3.x += f.x; a3.y += f.y;
            f = __builtin_amdgcn_cvt_pk_f32_fp8((int)q2.x, false); a0.x += f.x; a0.y += f.y;
            f = __builtin_amdgcn_cvt_pk_f32_fp8((int)q2.x, true);  a1.x += f.x; a1.y += f.y;
            f = __builtin_amdgcn_cvt_pk_f32_fp8((int)q2.y, false); a2.x += f.x; a2.y += f.y;
            f = __builtin_amdgcn_cvt_pk_f32_fp8((int)q2.y, true);  a3.x += f.x; a3.y += f.y;
            f = __builtin_amdgcn_cvt_pk_f32_fp8((int)q3.x, false); a0.x += f.x; a0.y += f.y;
            f = __builtin_amdgcn_cvt_pk_f32_fp8((int)q3.x, true);  a1.x += f.x; a1.y += f.y;
            f = __builtin_amdgcn_cvt_pk_f32_fp8((int)q3.y, false); a2.x += f.x; a2.y += f.y;
            f = __builtin_amdgcn_cvt_pk_f32_fp8((int)q3.y, true);  a3.x += f.x; a3.y += f.y;
        }
        for (; j < end; j += 4) {
            int idx = e_nodes[j];
            uint2 q = pr2[(size_t)idx * 16 + li];
            v2f f;
            f = __builtin_amdgcn_cvt_pk_f32_fp8((int)q.x, false); a0.x += f.x; a0.y += f.y;
            f = __builtin_amdgcn_cvt_pk_f32_fp8((int)q.x, true);  a1.x += f.x; a1.y += f.y;
            f = __builtin_amdgcn_cvt_pk_f32_fp8((int)q.y, false); a2.x += f.x; a2.y += f.y;
            f = __builtin_amdgcn_cvt_pk_f32_fp8((int)q.y, true);  a3.x += f.x; a3.y += f.y;
        }
        // combine the 4 lane-groups
        #pragma unroll
        for (int off = 16; off <= 32; off <<= 1) {
            a0.x += __shfl_xor(a0.x, off, 64); a0.y += __shfl_xor(a0.y, off, 64);
            a1.x += __shfl_xor(a1.x, off, 64); a1.y += __shfl_xor(a1.y, off, 64);
            a2.x += __shfl_xor(a2.x, off, 64); a2.y += __shfl_xor(a2.y, off, 64);
            a3.x += __shfl_xor(a3.x, off, 64); a3.y += __shfl_xor(a3.y, off, 64);
        }
        float inv = 1.0f / fmaxf((float)(end - beg), 1.0f);
        if (g == 0) {
            float* as = &a_s[wid * 4 + rr][li * 8];
            *(float4*)as       = make_float4(a0.x * inv, a0.y * inv, a1.x * inv, a1.y * inv);
            *(float4*)(as + 4) = make_float4(a2.x * inv, a2.y * inv, a3.x * inv, a3.y * inv);
        }
    }
    __syncthreads();

    // GEMM: thread (rq = tid>>6, jp = tid&63) computes rows rq*4..+3, cols jp*2,jp*2+1
    int rq = threadIdx.x >> 6;
    int jp = threadIdx.x & 63;
    float2 c0 = {0.f, 0.f}, c1 = {0.f, 0.f}, c2 = {0.f, 0.f}, c3 = {0.f, 0.f};
    for (int k = 0; k < K; k += 4) {
        float4 b0 = *(float4*)&a_s[rq * 4 + 0][k];
        float4 b1 = *(float4*)&a_s[rq * 4 + 1][k];
        float4 b2 = *(float4*)&a_s[rq * 4 + 2][k];
        float4 b3 = *(float4*)&a_s[rq * 4 + 3][k];
        float2 w0 = *(const float2*)&W[(k + 0) * K + jp * 2];
        float2 w1 = *(const float2*)&W[(k + 1) * K + jp * 2];
        float2 w2 = *(const float2*)&W[(k + 2) * K + jp * 2];
        float2 w3 = *(const float2*)&W[(k + 3) * K + jp * 2];
        c0.x += b0.x * w0.x + b0.y * w1.x + b0.z * w2.x + b0.w * w3.x;
        c0.y += b0.x * w0.y + b0.y * w1.y + b0.z * w2.y + b0.w * w3.y;
        c1.x += b1.x * w0.x + b1.y * w1.x + b1.z * w2.x + b1.w * w3.x;
        c1.y += b1.x * w0.y + b1.y * w1.y + b1.z * w2.y + b1.w * w3.y;
        c2.x += b2.x * w0.x + b2.y * w1.x + b2.z * w2.x + b2.w * w3.x;
        c2.y += b2.x * w0.y + b2.y * w1.y + b2.z * w2.y + b2.w * w3.y;
        c3.x += b3.x * w0.x + b3.y * w1.x + b3.z * w2.x + b3.w * w3.x;
        c3.y += b3.x * w0.y + b3.y * w1.y + b3.z * w2.y + b3.w * w3.y;
    }
    __half2* ef2 = (__half2*)edge_feat_h;
    int r0 = blockIdx.x * 16 + rq * 4;
    if (r0 + 0 < N_EDGES) ef2[(size_t)(r0 + 0) * 64 + jp] = __floats2half2_rn(c0.x, c0.y);
    if (r0 + 1 < N_EDGES) ef2[(size_t)(r0 + 1) * 64 + jp] = __floats2half2_rn(c1.x, c1.y);
    if (r0 + 2 < N_EDGES) ef2[(size_t)(r0 + 2) * 64 + jp] = __floats2half2_rn(c2.x, c2.y);
    if (r0 + 3 < N_EDGES) ef2[(size_t)(r0 + 3) * 64 + jp] = __floats2half2_rn(c3.x, c3.y);
}

// ------- fused: gather edge_feat(fp16, 4-deep MLP) -> node mean; nat-grad; mean-center -------
// 256 threads = 4 waves; block owns 16 nodes; wave owns 4 (lane-group g per node).
__global__ __launch_bounds__(256) void node_fin_k(const __half2* __restrict__ probs_h,
                                                  const int* __restrict__ n_off,
                                                  const int* __restrict__ n_edges,
                                                  const __half* __restrict__ edge_feat_h,
                                                  float* __restrict__ out) {
    int wid = threadIdx.x >> 6, lane = threadIdx.x & 63;
    int g = lane >> 4, li = lane & 15;
    int row = blockIdx.x * 16 + wid * 4 + g;      // 6250*16 == 100000 exactly
    int beg = n_off[row], end = n_off[row + 1];
    int deg = end - beg;

    const uint4* ef4 = (const uint4*)edge_feat_h;
    float2 a0 = {0.f, 0.f}, a1 = {0.f, 0.f}, a2 = {0.f, 0.f}, a3 = {0.f, 0.f};
    int t = beg;
    for (; t + 3 < end; t += 4) {
        int i0 = n_edges[t];
        int i1 = n_edges[t + 1];
        int i2 = n_edges[t + 2];
        int i3 = n_edges[t + 3];
        uint4 q0 = ef4[(size_t)i0 * 16 + li];
        uint4 q1 = ef4[(size_t)i1 * 16 + li];
        uint4 q2 = ef4[(size_t)i2 * 16 + li];
        uint4 q3 = ef4[(size_t)i3 * 16 + li];
        float2 f;
        f = __half22float2(*(__half2*)&q0.x); a0.x += f.x; a0.y += f.y;
        f = __half22float2(*(__half2*)&q0.y); a1.x += f.x; a1.y += f.y;
        f = __half22float2(*(__half2*)&q0.z); a2.x += f.x; a2.y += f.y;
        f = __half22float2(*(__half2*)&q0.w); a3.x += f.x; a3.y += f.y;
        f = __half22float2(*(__half2*)&q1.x); a0.x += f.x; a0.y += f.y;
        f = __half22float2(*(__half2*)&q1.y); a1.x += f.x; a1.y += f.y;
        f = __half22float2(*(__half2*)&q1.z); a2.x += f.x; a2.y += f.y;
        f = __half22float2(*(__half2*)&q1.w); a3.x += f.x; a3.y += f.y;
        f = __half22float2(*(__half2*)&q2.x); a0.x += f.x; a0.y += f.y;
        f = __half22float2(*(__half2*)&q2.y); a1.x += f.x; a1.y += f.y;
        f = __half22float2(*(__half2*)&q2.z); a2.x += f.x; a2.y += f.y;
        f = __half22float2(*(__half2*)&q2.w); a3.x += f.x; a3.y += f.y;
        f = __half22float2(*(__half2*)&q3.x); a0.x += f.x; a0.y += f.y;
        f = __half22float2(*(__half2*)&q3.y); a1.x += f.x; a1.y += f.y;
        f = __half22float2(*(__half2*)&q3.z); a2.x += f.x; a2.y += f.y;
        f = __half22float2(*(__half2*)&q3.w); a3.x += f.x; a3.y += f.y;
    }
    for (; t < end; ++t) {
        int idx = n_edges[t];
        uint4 q = ef4[(size_t)idx * 16 + li];
        float2 f;
        f = __half22float2(*(__half2*)&q.x); a0.x += f.x; a0.y += f.y;
        f = __half22float2(*(__half2*)&q.y); a1.x += f.x; a1.y += f.y;
        f = __half22float2(*(__half2*)&q.z); a2.x += f.x; a2.y += f.y;
        f = __half22float2(*(__half2*)&q.w); a3.x += f.x; a3.y += f.y;
    }
    float inv = 1.0f / fmaxf((float)deg, 1.0f);
    uint4 qp = ((const uint4*)probs_h)[(size_t)row * 16 + li];
    float2 p0 = __half22float2(*(__half2*)&qp.x);
    float2 p1 = __half22float2(*(__half2*)&qp.y);
    float2 p2 = __half22float2(*(__half2*)&qp.z);
    float2 p3 = __half22float2(*(__half2*)&qp.w);
    float v0 = fmaxf(p0.x, 1e-12f) * (a0.x * inv);
    float v1 = fmaxf(p0.y, 1e-12f) * (a0.y * inv);
    float v2 = fmaxf(p1.x, 1e-12f) * (a1.x * inv);
    float v3 = fmaxf(p1.y, 1e-12f) * (a1.y * inv);
    float v4 = fmaxf(p2.x, 1e-12f) * (a2.x * inv);
    float v5 = fmaxf(p2.y, 1e-12f) * (a2.y * inv);
    float v6 = fmaxf(p3.x, 1e-12f) * (a3.x * inv);
    float v7 = fmaxf(p3.y, 1e-12f) * (a3.y * inv);
    float s = ((v0 + v1) + (v2 + v3)) + ((v4 + v5) + (v6 + v7));
    #pragma unroll
    for (int off = 1; off <= 8; off <<= 1) s += __shfl_xor(s, off, 64);  // within 16-lane group
    float mean = s * (1.0f / (float)K);
    float* orow = out + (size_t)row * K + li * 8;
    *(float4*)orow       = make_float4(v0 - mean, v1 - mean, v2 - mean, v3 - mean);
    *(float4*)(orow + 4) = make_float4(v4 - mean, v5 - mean, v6 - mean, v7 - mean);
}

extern "C" void kernel_launch(void* const* d_in, const int* in_sizes, int n_in,
                              void* d_out, int out_size, void* d_ws, size_t ws_size,
                              hipStream_t stream) {
    const float* y        = (const float*)d_in[0];
    const float* W        = (const float*)d_in[1];
    const int*   node_idx = (const int*)d_in[2];
    const int*   edge_idx = (const int*)d_in[3];
    float* out = (float*)d_out;

    // workspace carve-up (4-byte units unless noted)
    unsigned* ebkt = (unsigned*)d_ws;                    // NNZ
    unsigned* nbkt = ebkt + NNZ;                         // NNZ
    int* e_nodes = (int*)(nbkt + NNZ);                   // NNZ
    int* n_edges = e_nodes + NNZ;                        // NNZ
    int* e_off   = n_edges + NNZ;                        // N_EDGES+1
    int* n_off   = e_off + (N_EDGES + 1);                // N_NODES+1
    int* ebcnt   = n_off + (N_NODES + 1);                // 200 (pad)
    int* nbcnt   = ebcnt + 200;                          // 200
    int* ebOff   = nbcnt + 200;                          // 200
    int* nbOff   = ebOff + 200;                          // 200
    int* ebCur   = nbOff + 200;                          // 200
    int* nbCur   = ebCur + 200;                          // 200
    uintptr_t pa = (uintptr_t)(nbCur + 200);
    pa = (pa + 255) & ~(uintptr_t)255;                   // 256B-align
    __half2* probs_h = (__half2*)pa;                     // N_NODES*64 half2 = 25.6 MB
    unsigned short* probs8 = (unsigned short*)(probs_h + (size_t)N_NODES * 64); // N_NODES*128 fp8 = 12.8 MB
    __half*  edge_feat_h = (__half*)ebkt;                // N_EDGES*K halves (6.4MB), aliases dead ebkt

    hipMemsetAsync(ebcnt, 0, 400 * sizeof(int), stream);

    bhist_k<<<1024, 256, 0, stream>>>(node_idx, edge_idx, ebcnt, nbcnt);
    bscan_k<<<1, 512, 0, stream>>>(ebcnt, nbcnt, ebOff, nbOff, ebCur, nbCur, e_off, n_off);
    bpart_k<<<(NNZ + 2047) / 2048, 256, 0, stream>>>(node_idx, edge_idx, ebCur, nbCur, ebkt, nbkt);
    bfill_k<<<NB_E + NB_N, 256, 0, stream>>>(ebkt, nbkt, ebOff, nbOff, e_off, n_off, e_nodes, n_edges);

    softmax_k<<<(N_NODES + 3) / 4, 256, 0, stream>>>(y, probs_h, probs8);
    mm2_k<<<(N_EDGES + 15) / 16, 256, 0, stream>>>((const unsigned*)probs8, e_off, e_nodes, W, edge_feat_h);
    node_fin_k<<<N_NODES / 16, 256, 0, stream>>>(probs_h, n_off, n_edges, edge_feat_h, out);
}